// Round 6
// baseline (645.714 us; speedup 1.0000x reference)
//
#include <hip/hip_runtime.h>
#include <hip/hip_fp16.h>

#define B_ 128
#define T_ 128
#define I_ 1024
#define O_ 1024
#define M_ (B_*T_)          // 16384 rows of h
#define NOUT (M_*O_)        // 16777216 spike outputs, loss at index NOUT

typedef __attribute__((ext_vector_type(8))) _Float16 half8;  // 8 fp16 = 4 VGPR
typedef __attribute__((ext_vector_type(4))) float floatx4;   // MFMA acc

// async global->LDS, 16B per lane. LDS dest = wave-uniform base + lane*16.
__device__ __forceinline__ void gld_lds16(const void* g, void* l) {
    __builtin_amdgcn_global_load_lds((const __attribute__((address_space(1))) void*)g,
                                     (__attribute__((address_space(3))) void*)l,
                                     16, 0, 0);
}

// Exact 3-way FP16 split: x = h + m + l + r with |r| <~ max(2^-33|x|, 2^-26).
// 6 kept cross-products (hh, hm, mh, mm, hl, lh) carry everything down to
// 2^-22 relative; dropped terms (ml, lm, ll) are <= 2^-33.
__device__ __forceinline__ void split3h(float x, unsigned short& h,
                                        unsigned short& m, unsigned short& l) {
    __half f0 = __float2half(x);
    float r1 = x - __half2float(f0);
    __half f1 = __float2half(r1);
    float r2 = r1 - __half2float(f1);
    __half f2 = __float2half(r2);
    h = __half_as_ushort(f0);
    m = __half_as_ushort(f1);
    l = __half_as_ushort(f2);
}

// ---------------------------------------------------------------------------
// split_x: x [M,K] f32 -> 3 fp16 planes, same layout. Pure memory pass.
// ---------------------------------------------------------------------------
__global__ __launch_bounds__(256) void split_x(const float* __restrict__ X,
                                               unsigned short* __restrict__ Xh,
                                               unsigned short* __restrict__ Xm,
                                               unsigned short* __restrict__ Xl) {
    size_t base = ((size_t)blockIdx.x * 256 + threadIdx.x) * 4;
    float4 v = *(const float4*)(X + base);
    ushort4 hh, mm, ll;
    split3h(v.x, hh.x, mm.x, ll.x);
    split3h(v.y, hh.y, mm.y, ll.y);
    split3h(v.z, hh.z, mm.z, ll.z);
    split3h(v.w, hh.w, mm.w, ll.w);
    *(ushort4*)(Xh + base) = hh;
    *(ushort4*)(Xm + base) = mm;
    *(ushort4*)(Xl + base) = ll;
}

// ---------------------------------------------------------------------------
// split_wt: w [K][N] f32 -> three TRANSPOSED fp16 planes wt_p[N][K].
// ---------------------------------------------------------------------------
__global__ __launch_bounds__(256) void split_wt(const float* __restrict__ W,
                                                unsigned short* __restrict__ WTh,
                                                unsigned short* __restrict__ WTm,
                                                unsigned short* __restrict__ WTl) {
    __shared__ float t[64][65];
    const int tid = threadIdx.x;
    const int tx = tid & 63, ty4 = tid >> 6;
    const int r0 = blockIdx.x * 64, c0 = blockIdx.y * 64;
#pragma unroll
    for (int j = 0; j < 16; ++j) {
        int row = j * 4 + ty4;
        t[row][tx] = W[(size_t)(r0 + row) * O_ + c0 + tx];
    }
    __syncthreads();
#pragma unroll
    for (int j = 0; j < 16; ++j) {
        int i = j * 4 + ty4;
        float v = t[tx][i];
        unsigned short h, m, l;
        split3h(v, h, m, l);
        size_t off = (size_t)(c0 + i) * I_ + r0 + tx;
        WTh[off] = h; WTm[off] = m; WTl[off] = l;
    }
}

// ---------------------------------------------------------------------------
// h = x @ w, fp16 3-way-split MFMA, 6 of 9 plane products (hh,hm,mh,mm,hl,lh).
// 128x256 tile, 512 threads, 8 waves x (64x64 output), double-buffered
// 6-plane LDS (2 x 72 KB = 144 KB, 1 block/CU). Stage for kt+1 issued at the
// top of kt's body. Verified 3x at 159-160us / MfmaUtil 59% / 0 conflicts.
// FROZEN this round.
// ---------------------------------------------------------------------------
__global__ __launch_bounds__(512, 2) void gemm_h_mfma(
        const unsigned short* __restrict__ Xh, const unsigned short* __restrict__ Xm,
        const unsigned short* __restrict__ Xl, const unsigned short* __restrict__ WTh,
        const unsigned short* __restrict__ WTm, const unsigned short* __restrict__ WTl,
        float* __restrict__ H) {
    const int K = I_, N = O_;
    __shared__ unsigned short P[2][36864];

    const int tid = threadIdx.x;
    const int lane = tid & 63;
    const int wid = tid >> 6;             // 0..7
    const int wrow = wid >> 2;            // 0..1 -> rows wrow*64
    const int wcol = wid & 3;             // 0..3 -> cols wcol*64
    const int l15 = lane & 15, quad = lane >> 4;
    const int bm = blockIdx.x * 128, bn = blockIdx.y * 256;

    const int srow = tid >> 2, sch = tid & 3;
    const int schg = sch ^ ((srow >> 1) & 3);
    const unsigned short* gsrcA[3];
    const unsigned short* gsrcB[3];
    gsrcA[0] = Xh  + (size_t)(bm + srow) * K + schg * 8;
    gsrcA[1] = Xm  + (size_t)(bm + srow) * K + schg * 8;
    gsrcA[2] = Xl  + (size_t)(bm + srow) * K + schg * 8;
    gsrcB[0] = WTh + (size_t)(bn + srow) * K + schg * 8;
    gsrcB[1] = WTm + (size_t)(bn + srow) * K + schg * 8;
    gsrcB[2] = WTl + (size_t)(bn + srow) * K + schg * 8;

    auto stage = [&](int kt) {
        unsigned short* wb = &P[0][0] + (size_t)(kt & 1) * 36864;
        const size_t k0 = (size_t)kt * 32;
#pragma unroll
        for (int p = 0; p < 3; ++p)
            gld_lds16(gsrcA[p] + k0, wb + p * 4096 + tid * 8);
#pragma unroll
        for (int p = 0; p < 3; ++p) {
            unsigned short* bb = wb + 12288 + p * 8192 + tid * 8;
            gld_lds16(gsrcB[p] + k0, bb);
            gld_lds16(gsrcB[p] + (size_t)128 * K + k0, bb + 4096);
        }
    };

    floatx4 acc[4][4];
#pragma unroll
    for (int mt = 0; mt < 4; ++mt)
#pragma unroll
        for (int nt = 0; nt < 4; ++nt) acc[mt][nt] = (floatx4)(0.f);

    stage(0);   // prologue

    for (int kt = 0; kt < 32; ++kt) {
        const unsigned short* rb = &P[0][0] + (size_t)(kt & 1) * 36864;

        asm volatile("" ::: "memory");
        __builtin_amdgcn_s_waitcnt(0x1F70);   // vmcnt(0), lgkm/exp no-wait
        __builtin_amdgcn_s_barrier();
        asm volatile("" ::: "memory");

        half8 Af[3][4];
#pragma unroll
        for (int pa = 0; pa < 3; ++pa)
#pragma unroll
            for (int mt = 0; mt < 4; ++mt) {
                const int row = wrow * 64 + mt * 16 + l15;
                const int chk = quad ^ ((row >> 1) & 3);
                Af[pa][mt] = *(const half8*)(rb + pa * 4096 + row * 32 + chk * 8);
            }

        if (kt < 31) stage(kt + 1);   // in flight across this step's MFMAs

#pragma unroll
        for (int pb = 0; pb < 3; ++pb) {
            half8 Bf[4];
#pragma unroll
            for (int nt = 0; nt < 4; ++nt) {
                const int col = wcol * 64 + nt * 16 + l15;
                const int chk = quad ^ ((col >> 1) & 3);
                Bf[nt] = *(const half8*)(rb + 12288 + pb * 8192 + col * 32 + chk * 8);
            }
#pragma unroll
            for (int nt = 0; nt < 4; ++nt)
#pragma unroll
                for (int mt = 0; mt < 4; ++mt) {
                    acc[mt][nt] = __builtin_amdgcn_mfma_f32_16x16x32_f16(Af[0][mt], Bf[nt], acc[mt][nt], 0, 0, 0);
                    if (pb < 2)
                        acc[mt][nt] = __builtin_amdgcn_mfma_f32_16x16x32_f16(Af[1][mt], Bf[nt], acc[mt][nt], 0, 0, 0);
                    if (pb == 0)
                        acc[mt][nt] = __builtin_amdgcn_mfma_f32_16x16x32_f16(Af[2][mt], Bf[nt], acc[mt][nt], 0, 0, 0);
                }
        }
    }

    // epilogue: C/D row = quad*4 + reg, col = lane&15
#pragma unroll
    for (int mt = 0; mt < 4; ++mt)
#pragma unroll
        for (int nt = 0; nt < 4; ++nt) {
            int grow = bm + wrow * 64 + mt * 16 + quad * 4;
            int gcol = bn + wcol * 64 + nt * 16 + l15;
            float* hp = H + (size_t)grow * N + gcol;
#pragma unroll
            for (int r = 0; r < 4; ++r) hp[(size_t)r * N] = acc[mt][nt][r];
        }
}

// ---------------------------------------------------------------------------
// d = w^T w   (fp32 exact-class, 256 blocks, ~25 us measured).
// ---------------------------------------------------------------------------
__global__ __launch_bounds__(256) void gemm_wtw(const float* __restrict__ W,
                                                float* __restrict__ D) {
    const int K = I_, N = O_;
    __shared__ float As[32][68];
    __shared__ float Bs[32][68];
    const int tid = threadIdx.x;
    const int tx = tid & 15, ty = tid >> 4;
    const int bj = blockIdx.x * 64, bo = blockIdx.y * 64;
    const int lr = tid >> 4;
    const int lc = (tid & 15) << 2;

    float acc[4][4];
#pragma unroll
    for (int m = 0; m < 4; m++)
#pragma unroll
        for (int n = 0; n < 4; n++) acc[m][n] = 0.f;

    for (int k0 = 0; k0 < K; k0 += 32) {
        float4 a0 = *(const float4*)(W + (size_t)(k0 + lr) * N + bj + lc);
        float4 a1 = *(const float4*)(W + (size_t)(k0 + lr + 16) * N + bj + lc);
        float4 b0 = *(const float4*)(W + (size_t)(k0 + lr) * N + bo + lc);
        float4 b1 = *(const float4*)(W + (size_t)(k0 + lr + 16) * N + bo + lc);
        __syncthreads();
        *(float4*)&As[lr][lc] = a0; *(float4*)&As[lr + 16][lc] = a1;
        *(float4*)&Bs[lr][lc] = b0; *(float4*)&Bs[lr + 16][lc] = b1;
        __syncthreads();
#pragma unroll
        for (int k = 0; k < 32; ++k) {
            float4 av = *(const float4*)&As[k][ty * 4];
            float4 bv = *(const float4*)&Bs[k][tx * 4];
            float am[4] = {av.x, av.y, av.z, av.w};
            float bb[4] = {bv.x, bv.y, bv.z, bv.w};
#pragma unroll
            for (int m = 0; m < 4; m++)
#pragma unroll
                for (int n = 0; n < 4; n++) acc[m][n] += am[m] * bb[n];
        }
    }
#pragma unroll
    for (int m = 0; m < 4; m++) {
        float4 v = make_float4(acc[m][0], acc[m][1], acc[m][2], acc[m][3]);
        *(float4*)(D + (size_t)(bj + ty * 4 + m) * N + bo + tx * 4) = v;
    }
}

// inv_norm[o] = 1/(d[o][o] + 1e-8); zero the spike counter; zero the dummy
// gather row (zrow, reused dead x_h region) used by the scan's padded batches.
__global__ void colnorm_diag(const float* __restrict__ D, float* __restrict__ invn,
                             unsigned int* __restrict__ counter,
                             float* __restrict__ zrow) {
    int o = blockIdx.x * 256 + threadIdx.x;
    if (o == 0) *counter = 0u;
    invn[o] = 1.0f / (D[(size_t)o * O_ + o] + 1e-8f);
    zrow[o] = 0.0f;
}

// ---------------------------------------------------------------------------
// Sequential scan, WAVE-SYNCHRONOUS (r6 rewrite): ONE 64-lane wave per
// sample. Lane owns 16 neurons, interleaved: slot k (k=0..15, k=g*4+c) maps
// to neuron o = g*256 + lane*4 + c  -> every global access (h, out, d-rows)
// is a perfectly coalesced float4 per 4-slot group.
// Spike state = 16-bit register mask per lane. Cross-lane picture = ONE
// __ballot(lm!=0) + readlane per spiking lane. NO LDS, NO barrier, NO
// atomics, no shfl broadcast — the r2-r5 protocol (barrier + cnt/lst LDS
// arrays + LDS atomicAdd) was the measured per-step critical path
// (~3800 cyc/step; the r5 gather widening moved nothing).
// Gather: wave-uniform scalar cursor walks the spike set; batches of 8 rows
// (32 independent dwordx4 loads, zrow-padded) -> ~1 L2 round-trip per step.
// Summation order = ascending j (deterministic); padding adds exact +0.0.
// Occupancy is irrelevant (latency-bound): 128 blocks x 1 wave.
// ---------------------------------------------------------------------------
__global__ __launch_bounds__(64) void scan_kernel(const float* __restrict__ h,
                                                  const float* __restrict__ d,
                                                  const float* __restrict__ invn,
                                                  const float* __restrict__ bias,
                                                  const float* __restrict__ beta,
                                                  const float* __restrict__ zrow,
                                                  float* __restrict__ out,
                                                  unsigned int* __restrict__ spike_count) {
    const int lane = threadIdx.x;          // 0..63
    const int b = blockIdx.x;
    const float betav = beta[0];
    const float omb = 1.0f - betav;
    const int base0 = lane * 4;            // + g*256 per group

    float4 mem[4], invn4[4], b4[4], hcur[4], hnext[4];
#pragma unroll
    for (int g = 0; g < 4; ++g) {
        mem[g] = make_float4(0.f, 0.f, 0.f, 0.f);
        invn4[g] = *(const float4*)(invn + base0 + g * 256);
        b4[g]   = *(const float4*)(bias + base0 + g * 256);
    }
    const float* hb = h + (size_t)b * T_ * O_;
    float* ob = out + (size_t)b * T_ * O_;
#pragma unroll
    for (int g = 0; g < 4; ++g) hcur[g] = *(const float4*)(hb + base0 + g * 256);

    unsigned int lm = 0u;          // my 16 spike bits (slot k)
    unsigned int local_count = 0u;

    for (int t = 0; t < T_; ++t) {
        // prefetch h_{t+1} early (consumed at end of step)
        if (t + 1 < T_) {
#pragma unroll
            for (int g = 0; g < 4; ++g)
                hnext[g] = *(const float4*)(hb + (size_t)(t + 1) * O_ + base0 + g * 256);
        } else {
#pragma unroll
            for (int g = 0; g < 4; ++g) hnext[g] = make_float4(0.f, 0.f, 0.f, 0.f);
        }

        float4 rst[4];
#pragma unroll
        for (int g = 0; g < 4; ++g) rst[g] = make_float4(0.f, 0.f, 0.f, 0.f);

        // ---- gather rst over the spiking set (wave-uniform cursor) ----
        unsigned long long am = __ballot(lm != 0u);   // lanes with any spike
        unsigned int cl = 0u;      // current source lane
        unsigned int clm = 0u;     // its remaining mask bits
        while (am != 0ull || clm != 0u) {
            const float* srcb[8];
#pragma unroll
            for (int k = 0; k < 8; ++k) {
                while (clm == 0u && am != 0ull) {
                    cl = (unsigned)__builtin_ctzll(am);
                    am &= am - 1ull;
                    clm = (unsigned)__builtin_amdgcn_readlane((int)lm, (int)cl) & 0xFFFFu;
                }
                if (clm != 0u) {
                    const int bbit = __builtin_ctz(clm);
                    clm &= clm - 1u;
                    const int j = ((bbit >> 2) << 8) + ((int)cl << 2) + (bbit & 3);
                    srcb[k] = d + (size_t)j * O_;
                } else {
                    srcb[k] = zrow;            // exact +0.0 padding
                }
            }
            float4 vv[8][4];
#pragma unroll
            for (int k = 0; k < 8; ++k)
#pragma unroll
                for (int g = 0; g < 4; ++g)
                    vv[k][g] = *(const float4*)(srcb[k] + base0 + g * 256);
#pragma unroll
            for (int k = 0; k < 8; ++k)
#pragma unroll
                for (int g = 0; g < 4; ++g) {
                    rst[g].x += vv[k][g].x; rst[g].y += vv[k][g].y;
                    rst[g].z += vv[k][g].z; rst[g].w += vv[k][g].w;
                }
        }

        // ---- mem update, spike, output, new mask ----
        unsigned int nlm = 0u;
#pragma unroll
        for (int g = 0; g < 4; ++g) {
            mem[g].x = (mem[g].x - rst[g].x) * betav + hcur[g].x * omb;
            mem[g].y = (mem[g].y - rst[g].y) * betav + hcur[g].y * omb;
            mem[g].z = (mem[g].z - rst[g].z) * betav + hcur[g].z * omb;
            mem[g].w = (mem[g].w - rst[g].w) * betav + hcur[g].w * omb;
            const int s0 = (mem[g].x * invn4[g].x - b4[g].x) > 0.0f;
            const int s1 = (mem[g].y * invn4[g].y - b4[g].y) > 0.0f;
            const int s2 = (mem[g].z * invn4[g].z - b4[g].z) > 0.0f;
            const int s3 = (mem[g].w * invn4[g].w - b4[g].w) > 0.0f;
            nlm |= ((unsigned)s0 << (g * 4 + 0)) | ((unsigned)s1 << (g * 4 + 1)) |
                   ((unsigned)s2 << (g * 4 + 2)) | ((unsigned)s3 << (g * 4 + 3));
            float4 sv = make_float4(s0 ? 1.f : 0.f, s1 ? 1.f : 0.f,
                                    s2 ? 1.f : 0.f, s3 ? 1.f : 0.f);
            *(float4*)(ob + (size_t)t * O_ + base0 + g * 256) = sv;
            local_count += (unsigned)(s0 + s1 + s2 + s3);
        }
        lm = nlm;
#pragma unroll
        for (int g = 0; g < 4; ++g) hcur[g] = hnext[g];
    }

    // wave-reduce local_count, one global atomic per block
#pragma unroll
    for (int off = 32; off > 0; off >>= 1)
        local_count += (unsigned)__shfl_down((int)local_count, off, 64);
    if (lane == 0) atomicAdd(spike_count, local_count);
}

__global__ void finalize_loss(const unsigned int* __restrict__ spike_count,
                              float* __restrict__ loss_out) {
    *loss_out = 0.5f * ((float)(*spike_count) / 16777216.0f);
}

// ---------------------------------------------------------------------------
extern "C" void kernel_launch(void* const* d_in, const int* in_sizes, int n_in,
                              void* d_out, int out_size, void* d_ws, size_t ws_size,
                              hipStream_t stream) {
    const float* x    = (const float*)d_in[0];   // [B,T,I]
    const float* w    = (const float*)d_in[1];   // [I,O]
    const float* beta = (const float*)d_in[2];   // [1]
    const float* bias = (const float*)d_in[3];   // [O]
    float* out = (float*)d_out;                  // NOUT spikes + 1 loss

    // workspace layout (~170 MB)
    char* ws = (char*)d_ws;
    float* h    = (float*)ws;                                         // 64 MiB
    float* dmat = (float*)(ws + (size_t)67108864);                    // 4 MiB
    float* invn = (float*)(ws + (size_t)71303168);                    // 4 KiB
    unsigned int* cntp = (unsigned int*)(ws + (size_t)71307264);      // 4 KiB
    unsigned short* wt_h = (unsigned short*)(ws + (size_t)71311360);  // 2 MiB
    unsigned short* wt_m = (unsigned short*)(ws + (size_t)73408512);  // 2 MiB
    unsigned short* wt_l = (unsigned short*)(ws + (size_t)75505664);  // 2 MiB
    unsigned short* x_h  = (unsigned short*)(ws + (size_t)77602816);  // 32 MiB
    unsigned short* x_m  = (unsigned short*)(ws + (size_t)111157248); // 32 MiB
    unsigned short* x_l  = (unsigned short*)(ws + (size_t)144711680); // 32 MiB
    float* zrow = (float*)x_h;   // dead after gemm_h; zeroed by colnorm_diag

    split_x<<<M_ * I_ / 1024, 256, 0, stream>>>(x, x_h, x_m, x_l);
    split_wt<<<dim3(I_ / 64, O_ / 64), 256, 0, stream>>>(w, wt_h, wt_m, wt_l);
    gemm_h_mfma<<<dim3(M_ / 128, O_ / 256), 512, 0, stream>>>(x_h, x_m, x_l,
                                                              wt_h, wt_m, wt_l, h);
    gemm_wtw<<<dim3(O_ / 64, O_ / 64), 256, 0, stream>>>(w, dmat);
    colnorm_diag<<<O_ / 256, 256, 0, stream>>>(dmat, invn, cntp, zrow);
    scan_kernel<<<B_, 64, 0, stream>>>(h, dmat, invn, bias, beta, zrow, out, cntp);
    finalize_loss<<<1, 1, 0, stream>>>(cntp, out + (size_t)NOUT);
}

// Round 7
// 605.168 us; speedup vs baseline: 1.0670x; 1.0670x over previous
//
#include <hip/hip_runtime.h>
#include <hip/hip_fp16.h>

#define B_ 128
#define T_ 128
#define I_ 1024
#define O_ 1024
#define M_ (B_*T_)          // 16384 rows of h
#define NOUT (M_*O_)        // 16777216 spike outputs, loss at index NOUT

typedef __attribute__((ext_vector_type(8))) _Float16 half8;  // 8 fp16 = 4 VGPR
typedef __attribute__((ext_vector_type(4))) float floatx4;   // MFMA acc

// async global->LDS, 16B per lane. LDS dest = wave-uniform base + lane*16.
__device__ __forceinline__ void gld_lds16(const void* g, void* l) {
    __builtin_amdgcn_global_load_lds((const __attribute__((address_space(1))) void*)g,
                                     (__attribute__((address_space(3))) void*)l,
                                     16, 0, 0);
}

// Workgroup barrier that waits ONLY on LDS ops (lgkmcnt(0)); does NOT drain
// vmcnt. 0xC07F = vmcnt 63 (bits 3:0 & 15:14), expcnt 7, lgkmcnt 0.
__device__ __forceinline__ void barrier_lds_only() {
    asm volatile("" ::: "memory");
    __builtin_amdgcn_s_waitcnt(0xC07F);
    __builtin_amdgcn_s_barrier();
    asm volatile("" ::: "memory");
}

// Exact 3-way FP16 split: x = h + m + l + r with |r| <~ max(2^-33|x|, 2^-26).
// 6 kept cross-products (hh, hm, mh, mm, hl, lh) carry everything down to
// 2^-22 relative; dropped terms (ml, lm, ll) are <= 2^-33.
__device__ __forceinline__ void split3h(float x, unsigned short& h,
                                        unsigned short& m, unsigned short& l) {
    __half f0 = __float2half(x);
    float r1 = x - __half2float(f0);
    __half f1 = __float2half(r1);
    float r2 = r1 - __half2float(f1);
    __half f2 = __float2half(r2);
    h = __half_as_ushort(f0);
    m = __half_as_ushort(f1);
    l = __half_as_ushort(f2);
}

// ---------------------------------------------------------------------------
// split_x: x [M,K] f32 -> 3 fp16 planes, same layout. Pure memory pass.
// ---------------------------------------------------------------------------
__global__ __launch_bounds__(256) void split_x(const float* __restrict__ X,
                                               unsigned short* __restrict__ Xh,
                                               unsigned short* __restrict__ Xm,
                                               unsigned short* __restrict__ Xl) {
    size_t base = ((size_t)blockIdx.x * 256 + threadIdx.x) * 4;
    float4 v = *(const float4*)(X + base);
    ushort4 hh, mm, ll;
    split3h(v.x, hh.x, mm.x, ll.x);
    split3h(v.y, hh.y, mm.y, ll.y);
    split3h(v.z, hh.z, mm.z, ll.z);
    split3h(v.w, hh.w, mm.w, ll.w);
    *(ushort4*)(Xh + base) = hh;
    *(ushort4*)(Xm + base) = mm;
    *(ushort4*)(Xl + base) = ll;
}

// ---------------------------------------------------------------------------
// split_wt: w [K][N] f32 -> three TRANSPOSED fp16 planes wt_p[N][K].
// ---------------------------------------------------------------------------
__global__ __launch_bounds__(256) void split_wt(const float* __restrict__ W,
                                                unsigned short* __restrict__ WTh,
                                                unsigned short* __restrict__ WTm,
                                                unsigned short* __restrict__ WTl) {
    __shared__ float t[64][65];
    const int tid = threadIdx.x;
    const int tx = tid & 63, ty4 = tid >> 6;
    const int r0 = blockIdx.x * 64, c0 = blockIdx.y * 64;
#pragma unroll
    for (int j = 0; j < 16; ++j) {
        int row = j * 4 + ty4;
        t[row][tx] = W[(size_t)(r0 + row) * O_ + c0 + tx];
    }
    __syncthreads();
#pragma unroll
    for (int j = 0; j < 16; ++j) {
        int i = j * 4 + ty4;
        float v = t[tx][i];
        unsigned short h, m, l;
        split3h(v, h, m, l);
        size_t off = (size_t)(c0 + i) * I_ + r0 + tx;
        WTh[off] = h; WTm[off] = m; WTl[off] = l;
    }
}

// ---------------------------------------------------------------------------
// h = x @ w, fp16 3-way-split MFMA, 6 of 9 plane products (hh,hm,mh,mm,hl,lh).
// 128x256 tile, 512 threads, 8 waves x (64x64 output), double-buffered
// 6-plane LDS (2 x 72 KB = 144 KB, 1 block/CU). Stage for kt+1 issued at the
// top of kt's body. Verified 3x at 159-160us / MfmaUtil 59% / 0 conflicts.
// FROZEN.
// ---------------------------------------------------------------------------
__global__ __launch_bounds__(512, 2) void gemm_h_mfma(
        const unsigned short* __restrict__ Xh, const unsigned short* __restrict__ Xm,
        const unsigned short* __restrict__ Xl, const unsigned short* __restrict__ WTh,
        const unsigned short* __restrict__ WTm, const unsigned short* __restrict__ WTl,
        float* __restrict__ H) {
    const int K = I_, N = O_;
    __shared__ unsigned short P[2][36864];

    const int tid = threadIdx.x;
    const int lane = tid & 63;
    const int wid = tid >> 6;             // 0..7
    const int wrow = wid >> 2;            // 0..1 -> rows wrow*64
    const int wcol = wid & 3;             // 0..3 -> cols wcol*64
    const int l15 = lane & 15, quad = lane >> 4;
    const int bm = blockIdx.x * 128, bn = blockIdx.y * 256;

    const int srow = tid >> 2, sch = tid & 3;
    const int schg = sch ^ ((srow >> 1) & 3);
    const unsigned short* gsrcA[3];
    const unsigned short* gsrcB[3];
    gsrcA[0] = Xh  + (size_t)(bm + srow) * K + schg * 8;
    gsrcA[1] = Xm  + (size_t)(bm + srow) * K + schg * 8;
    gsrcA[2] = Xl  + (size_t)(bm + srow) * K + schg * 8;
    gsrcB[0] = WTh + (size_t)(bn + srow) * K + schg * 8;
    gsrcB[1] = WTm + (size_t)(bn + srow) * K + schg * 8;
    gsrcB[2] = WTl + (size_t)(bn + srow) * K + schg * 8;

    auto stage = [&](int kt) {
        unsigned short* wb = &P[0][0] + (size_t)(kt & 1) * 36864;
        const size_t k0 = (size_t)kt * 32;
#pragma unroll
        for (int p = 0; p < 3; ++p)
            gld_lds16(gsrcA[p] + k0, wb + p * 4096 + tid * 8);
#pragma unroll
        for (int p = 0; p < 3; ++p) {
            unsigned short* bb = wb + 12288 + p * 8192 + tid * 8;
            gld_lds16(gsrcB[p] + k0, bb);
            gld_lds16(gsrcB[p] + (size_t)128 * K + k0, bb + 4096);
        }
    };

    floatx4 acc[4][4];
#pragma unroll
    for (int mt = 0; mt < 4; ++mt)
#pragma unroll
        for (int nt = 0; nt < 4; ++nt) acc[mt][nt] = (floatx4)(0.f);

    stage(0);   // prologue

    for (int kt = 0; kt < 32; ++kt) {
        const unsigned short* rb = &P[0][0] + (size_t)(kt & 1) * 36864;

        asm volatile("" ::: "memory");
        __builtin_amdgcn_s_waitcnt(0x1F70);   // vmcnt(0), lgkm/exp no-wait
        __builtin_amdgcn_s_barrier();
        asm volatile("" ::: "memory");

        half8 Af[3][4];
#pragma unroll
        for (int pa = 0; pa < 3; ++pa)
#pragma unroll
            for (int mt = 0; mt < 4; ++mt) {
                const int row = wrow * 64 + mt * 16 + l15;
                const int chk = quad ^ ((row >> 1) & 3);
                Af[pa][mt] = *(const half8*)(rb + pa * 4096 + row * 32 + chk * 8);
            }

        if (kt < 31) stage(kt + 1);   // in flight across this step's MFMAs

#pragma unroll
        for (int pb = 0; pb < 3; ++pb) {
            half8 Bf[4];
#pragma unroll
            for (int nt = 0; nt < 4; ++nt) {
                const int col = wcol * 64 + nt * 16 + l15;
                const int chk = quad ^ ((col >> 1) & 3);
                Bf[nt] = *(const half8*)(rb + 12288 + pb * 8192 + col * 32 + chk * 8);
            }
#pragma unroll
            for (int nt = 0; nt < 4; ++nt)
#pragma unroll
                for (int mt = 0; mt < 4; ++mt) {
                    acc[mt][nt] = __builtin_amdgcn_mfma_f32_16x16x32_f16(Af[0][mt], Bf[nt], acc[mt][nt], 0, 0, 0);
                    if (pb < 2)
                        acc[mt][nt] = __builtin_amdgcn_mfma_f32_16x16x32_f16(Af[1][mt], Bf[nt], acc[mt][nt], 0, 0, 0);
                    if (pb == 0)
                        acc[mt][nt] = __builtin_amdgcn_mfma_f32_16x16x32_f16(Af[2][mt], Bf[nt], acc[mt][nt], 0, 0, 0);
                }
        }
    }

    // epilogue: C/D row = quad*4 + reg, col = lane&15
#pragma unroll
    for (int mt = 0; mt < 4; ++mt)
#pragma unroll
        for (int nt = 0; nt < 4; ++nt) {
            int grow = bm + wrow * 64 + mt * 16 + quad * 4;
            int gcol = bn + wcol * 64 + nt * 16 + l15;
            float* hp = H + (size_t)grow * N + gcol;
#pragma unroll
            for (int r = 0; r < 4; ++r) hp[(size_t)r * N] = acc[mt][nt][r];
        }
}

// ---------------------------------------------------------------------------
// d = w^T w   (fp32 exact-class, 256 blocks, ~25 us measured).
// ---------------------------------------------------------------------------
__global__ __launch_bounds__(256) void gemm_wtw(const float* __restrict__ W,
                                                float* __restrict__ D) {
    const int K = I_, N = O_;
    __shared__ float As[32][68];
    __shared__ float Bs[32][68];
    const int tid = threadIdx.x;
    const int tx = tid & 15, ty = tid >> 4;
    const int bj = blockIdx.x * 64, bo = blockIdx.y * 64;
    const int lr = tid >> 4;
    const int lc = (tid & 15) << 2;

    float acc[4][4];
#pragma unroll
    for (int m = 0; m < 4; m++)
#pragma unroll
        for (int n = 0; n < 4; n++) acc[m][n] = 0.f;

    for (int k0 = 0; k0 < K; k0 += 32) {
        float4 a0 = *(const float4*)(W + (size_t)(k0 + lr) * N + bj + lc);
        float4 a1 = *(const float4*)(W + (size_t)(k0 + lr + 16) * N + bj + lc);
        float4 b0 = *(const float4*)(W + (size_t)(k0 + lr) * N + bo + lc);
        float4 b1 = *(const float4*)(W + (size_t)(k0 + lr + 16) * N + bo + lc);
        __syncthreads();
        *(float4*)&As[lr][lc] = a0; *(float4*)&As[lr + 16][lc] = a1;
        *(float4*)&Bs[lr][lc] = b0; *(float4*)&Bs[lr + 16][lc] = b1;
        __syncthreads();
#pragma unroll
        for (int k = 0; k < 32; ++k) {
            float4 av = *(const float4*)&As[k][ty * 4];
            float4 bv = *(const float4*)&Bs[k][tx * 4];
            float am[4] = {av.x, av.y, av.z, av.w};
            float bb[4] = {bv.x, bv.y, bv.z, bv.w};
#pragma unroll
            for (int m = 0; m < 4; m++)
#pragma unroll
                for (int n = 0; n < 4; n++) acc[m][n] += am[m] * bb[n];
        }
    }
#pragma unroll
    for (int m = 0; m < 4; m++) {
        float4 v = make_float4(acc[m][0], acc[m][1], acc[m][2], acc[m][3]);
        *(float4*)(D + (size_t)(bj + ty * 4 + m) * N + bo + tx * 4) = v;
    }
}

// inv_norm[o] = 1/(d[o][o] + 1e-8); zero the spike counter; zero the dummy
// gather row (zrow, reused dead x_h region) used by the scan's padded batches.
__global__ void colnorm_diag(const float* __restrict__ D, float* __restrict__ invn,
                             unsigned int* __restrict__ counter,
                             float* __restrict__ zrow) {
    int o = blockIdx.x * 256 + threadIdx.x;
    if (o == 0) *counter = 0u;
    invn[o] = 1.0f / (D[(size_t)o * O_ + o] + 1e-8f);
    zrow[o] = 0.0f;
}

// ---------------------------------------------------------------------------
// Sequential scan, r7: TWO SAMPLES PER BLOCK (64 blocks x 512 threads).
// Restores the r5 8-wave LDS-append protocol (measured best) and amortizes
// the fixed per-step serial chain — barrier, cnt read, lst reads, d-row L2
// latency, atomic+shfl append — over two independent samples processed in
// the same traversal. The two chains share one barrier; their LDS reads,
// d-loads (16 in flight) and updates interleave as pure ILP.
// n ~ 8 spikes/step (P(mem>thr) ~ 0.9%), so the gather is one 8-batch per
// sample (zrow-padded: exact +0.0).
// Race-safety: one barrier per step; step-t appends -> lst*[(t+1)&1], step-t
// reads <- lst*[t&1] (disjoint between consecutive barriers).
// ---------------------------------------------------------------------------
__global__ __launch_bounds__(512) void scan_kernel(const float* __restrict__ h,
                                                   const float* __restrict__ d,
                                                   const float* __restrict__ invn,
                                                   const float* __restrict__ bias,
                                                   const float* __restrict__ beta,
                                                   const float* __restrict__ zrow,
                                                   float* __restrict__ out,
                                                   unsigned int* __restrict__ spike_count) {
    __shared__ int lstA[2][O_], lstB[2][O_];
    __shared__ int cntA[T_ + 1], cntB[T_ + 1];
    __shared__ unsigned int red[512];

    const int tid = threadIdx.x;
    const int lane = tid & 63;
    const int bA = blockIdx.x;
    const int bB = blockIdx.x + 64;
    const int o2 = tid * 2;
    const float betav = beta[0];
    const float omb = 1.0f - betav;

    const float2 invn2 = *(const float2*)(invn + o2);
    const float2 b2 = *(const float2*)(bias + o2);
    float2 memA = make_float2(0.f, 0.f), memB = make_float2(0.f, 0.f);

    for (int i = tid; i <= T_; i += 512) { cntA[i] = 0; cntB[i] = 0; }
    unsigned int local_count = 0;
    const float* hbA = h + (size_t)bA * T_ * O_;
    const float* hbB = h + (size_t)bB * T_ * O_;
    float* obA = out + (size_t)bA * T_ * O_;
    float* obB = out + (size_t)bB * T_ * O_;
    const float* zp = zrow + o2;
    const unsigned long long below = (lane == 63) ? 0xFFFFFFFFFFFFFFFFull >> 1
                                                  : ((1ull << lane) - 1ull);

    float2 hcurA = *(const float2*)(hbA + o2);
    float2 hcurB = *(const float2*)(hbB + o2);
    __syncthreads();

    for (int t = 0; t < T_; ++t) {
        const int p = t & 1, q = p ^ 1;
        const int nA = cntA[t], nB = cntB[t];

        float2 hnextA = make_float2(0.f, 0.f), hnextB = make_float2(0.f, 0.f);
        if (t + 1 < T_) {
            hnextA = *(const float2*)(hbA + (size_t)(t + 1) * O_ + o2);
            hnextB = *(const float2*)(hbB + (size_t)(t + 1) * O_ + o2);
        }

        float2 rstA = make_float2(0.f, 0.f), rstB = make_float2(0.f, 0.f);
        const int nmax = (nA > nB) ? nA : nB;
        for (int i = 0; i < nmax; i += 8) {
            const float* srcA[8];
            const float* srcB[8];
#pragma unroll
            for (int u = 0; u < 8; ++u) {
                const int idx = i + u;
                const int jA = lstA[p][idx & (O_ - 1)];
                const int jB = lstB[p][idx & (O_ - 1)];
                srcA[u] = (idx < nA) ? (d + (size_t)jA * O_ + o2) : zp;
                srcB[u] = (idx < nB) ? (d + (size_t)jB * O_ + o2) : zp;
            }
            float2 vA[8], vB[8];
#pragma unroll
            for (int u = 0; u < 8; ++u) { vA[u] = *(const float2*)srcA[u];
                                          vB[u] = *(const float2*)srcB[u]; }
#pragma unroll
            for (int u = 0; u < 8; ++u) {
                rstA.x += vA[u].x; rstA.y += vA[u].y;
                rstB.x += vB[u].x; rstB.y += vB[u].y;
            }
        }

        memA.x = (memA.x - rstA.x) * betav + hcurA.x * omb;
        memA.y = (memA.y - rstA.y) * betav + hcurA.y * omb;
        memB.x = (memB.x - rstB.x) * betav + hcurB.x * omb;
        memB.y = (memB.y - rstB.y) * betav + hcurB.y * omb;

        const int sA0 = (memA.x * invn2.x - b2.x) > 0.0f;
        const int sA1 = (memA.y * invn2.y - b2.y) > 0.0f;
        const int sB0 = (memB.x * invn2.x - b2.x) > 0.0f;
        const int sB1 = (memB.y * invn2.y - b2.y) > 0.0f;

        *(float2*)(obA + (size_t)t * O_ + o2) =
            make_float2(sA0 ? 1.f : 0.f, sA1 ? 1.f : 0.f);
        *(float2*)(obB + (size_t)t * O_ + o2) =
            make_float2(sB0 ? 1.f : 0.f, sB1 ? 1.f : 0.f);
        local_count += (unsigned)(sA0 + sA1 + sB0 + sB1);

        // ballot-aggregated appends: ONE LDS atomic per wave per sample
        unsigned long long mA0 = __ballot(sA0);
        unsigned long long mA1 = __ballot(sA1);
        unsigned long long mB0 = __ballot(sB0);
        unsigned long long mB1 = __ballot(sB1);
        const int cA0 = __popcll(mA0);
        const int cB0 = __popcll(mB0);
        const int totA = cA0 + __popcll(mA1);
        const int totB = cB0 + __popcll(mB1);
        int baseA = 0, baseB = 0;
        if (lane == 0) {
            if (totA) baseA = atomicAdd(&cntA[t + 1], totA);
            if (totB) baseB = atomicAdd(&cntB[t + 1], totB);
        }
        baseA = __shfl(baseA, 0, 64);
        baseB = __shfl(baseB, 0, 64);
        if (sA0) lstA[q][baseA + __popcll(mA0 & below)] = o2 + 0;
        if (sA1) lstA[q][baseA + cA0 + __popcll(mA1 & below)] = o2 + 1;
        if (sB0) lstB[q][baseB + __popcll(mB0 & below)] = o2 + 0;
        if (sB1) lstB[q][baseB + cB0 + __popcll(mB1 & below)] = o2 + 1;

        barrier_lds_only();
        hcurA = hnextA;
        hcurB = hnextB;
    }

    red[tid] = local_count;
    __syncthreads();
    for (int st = 256; st > 0; st >>= 1) {
        if (tid < st) red[tid] += red[tid + st];
        __syncthreads();
    }
    if (tid == 0) atomicAdd(spike_count, red[0]);
}

__global__ void finalize_loss(const unsigned int* __restrict__ spike_count,
                              float* __restrict__ loss_out) {
    *loss_out = 0.5f * ((float)(*spike_count) / 16777216.0f);
}

// ---------------------------------------------------------------------------
extern "C" void kernel_launch(void* const* d_in, const int* in_sizes, int n_in,
                              void* d_out, int out_size, void* d_ws, size_t ws_size,
                              hipStream_t stream) {
    const float* x    = (const float*)d_in[0];   // [B,T,I]
    const float* w    = (const float*)d_in[1];   // [I,O]
    const float* beta = (const float*)d_in[2];   // [1]
    const float* bias = (const float*)d_in[3];   // [O]
    float* out = (float*)d_out;                  // NOUT spikes + 1 loss

    // workspace layout (~170 MB)
    char* ws = (char*)d_ws;
    float* h    = (float*)ws;                                         // 64 MiB
    float* dmat = (float*)(ws + (size_t)67108864);                    // 4 MiB
    float* invn = (float*)(ws + (size_t)71303168);                    // 4 KiB
    unsigned int* cntp = (unsigned int*)(ws + (size_t)71307264);      // 4 KiB
    unsigned short* wt_h = (unsigned short*)(ws + (size_t)71311360);  // 2 MiB
    unsigned short* wt_m = (unsigned short*)(ws + (size_t)73408512);  // 2 MiB
    unsigned short* wt_l = (unsigned short*)(ws + (size_t)75505664);  // 2 MiB
    unsigned short* x_h  = (unsigned short*)(ws + (size_t)77602816);  // 32 MiB
    unsigned short* x_m  = (unsigned short*)(ws + (size_t)111157248); // 32 MiB
    unsigned short* x_l  = (unsigned short*)(ws + (size_t)144711680); // 32 MiB
    float* zrow = (float*)x_h;   // dead after gemm_h; zeroed by colnorm_diag

    split_x<<<M_ * I_ / 1024, 256, 0, stream>>>(x, x_h, x_m, x_l);
    split_wt<<<dim3(I_ / 64, O_ / 64), 256, 0, stream>>>(w, wt_h, wt_m, wt_l);
    gemm_h_mfma<<<dim3(M_ / 128, O_ / 256), 512, 0, stream>>>(x_h, x_m, x_l,
                                                              wt_h, wt_m, wt_l, h);
    gemm_wtw<<<dim3(O_ / 64, O_ / 64), 256, 0, stream>>>(w, dmat);
    colnorm_diag<<<O_ / 256, 256, 0, stream>>>(dmat, invn, cntp, zrow);
    scan_kernel<<<B_ / 2, 512, 0, stream>>>(h, dmat, invn, bias, beta, zrow, out, cntp);
    finalize_loss<<<1, 1, 0, stream>>>(cntp, out + (size_t)NOUT);
}

// Round 8
// 519.124 us; speedup vs baseline: 1.2439x; 1.1657x over previous
//
#include <hip/hip_runtime.h>
#include <hip/hip_fp16.h>

#define B_ 128
#define T_ 128
#define I_ 1024
#define O_ 1024
#define M_ (B_*T_)          // 16384 rows of h
#define NOUT (M_*O_)        // 16777216 spike outputs, loss at index NOUT

typedef __attribute__((ext_vector_type(8))) _Float16 half8;  // 8 fp16 = 4 VGPR
typedef __attribute__((ext_vector_type(4))) float floatx4;   // MFMA acc

// async global->LDS, 16B per lane. LDS dest = wave-uniform base + lane*16.
__device__ __forceinline__ void gld_lds16(const void* g, void* l) {
    __builtin_amdgcn_global_load_lds((const __attribute__((address_space(1))) void*)g,
                                     (__attribute__((address_space(3))) void*)l,
                                     16, 0, 0);
}

// Workgroup barrier that waits ONLY on LDS ops (lgkmcnt(0)); does NOT drain
// vmcnt. 0xC07F = vmcnt 63 (bits 3:0 & 15:14), expcnt 7, lgkmcnt 0.
__device__ __forceinline__ void barrier_lds_only() {
    asm volatile("" ::: "memory");
    __builtin_amdgcn_s_waitcnt(0xC07F);
    __builtin_amdgcn_s_barrier();
    asm volatile("" ::: "memory");
}

// Exact 3-way FP16 split: x = h + m + l + r with |r| <~ max(2^-33|x|, 2^-26).
// 6 kept cross-products (hh, hm, mh, mm, hl, lh) carry everything down to
// 2^-22 relative; dropped terms (ml, lm, ll) are <= 2^-33.
__device__ __forceinline__ void split3h(float x, unsigned short& h,
                                        unsigned short& m, unsigned short& l) {
    __half f0 = __float2half(x);
    float r1 = x - __half2float(f0);
    __half f1 = __float2half(r1);
    float r2 = r1 - __half2float(f1);
    __half f2 = __float2half(r2);
    h = __half_as_ushort(f0);
    m = __half_as_ushort(f1);
    l = __half_as_ushort(f2);
}

// ---------------------------------------------------------------------------
// split_x: x [M,K] f32 -> 3 fp16 planes, same layout. Pure memory pass.
// ---------------------------------------------------------------------------
__global__ __launch_bounds__(256) void split_x(const float* __restrict__ X,
                                               unsigned short* __restrict__ Xh,
                                               unsigned short* __restrict__ Xm,
                                               unsigned short* __restrict__ Xl) {
    size_t base = ((size_t)blockIdx.x * 256 + threadIdx.x) * 4;
    float4 v = *(const float4*)(X + base);
    ushort4 hh, mm, ll;
    split3h(v.x, hh.x, mm.x, ll.x);
    split3h(v.y, hh.y, mm.y, ll.y);
    split3h(v.z, hh.z, mm.z, ll.z);
    split3h(v.w, hh.w, mm.w, ll.w);
    *(ushort4*)(Xh + base) = hh;
    *(ushort4*)(Xm + base) = mm;
    *(ushort4*)(Xl + base) = ll;
}

// ---------------------------------------------------------------------------
// split_wt: w [K][N] f32 -> three TRANSPOSED fp16 planes wt_p[N][K].
// ---------------------------------------------------------------------------
__global__ __launch_bounds__(256) void split_wt(const float* __restrict__ W,
                                                unsigned short* __restrict__ WTh,
                                                unsigned short* __restrict__ WTm,
                                                unsigned short* __restrict__ WTl) {
    __shared__ float t[64][65];
    const int tid = threadIdx.x;
    const int tx = tid & 63, ty4 = tid >> 6;
    const int r0 = blockIdx.x * 64, c0 = blockIdx.y * 64;
#pragma unroll
    for (int j = 0; j < 16; ++j) {
        int row = j * 4 + ty4;
        t[row][tx] = W[(size_t)(r0 + row) * O_ + c0 + tx];
    }
    __syncthreads();
#pragma unroll
    for (int j = 0; j < 16; ++j) {
        int i = j * 4 + ty4;
        float v = t[tx][i];
        unsigned short h, m, l;
        split3h(v, h, m, l);
        size_t off = (size_t)(c0 + i) * I_ + r0 + tx;
        WTh[off] = h; WTm[off] = m; WTl[off] = l;
    }
}

// ---------------------------------------------------------------------------
// h = x @ w, fp16 3-way-split MFMA, 6 of 9 plane products (hh,hm,mh,mm,hl,lh).
// 128x256 tile, 512 threads, 8 waves x (64x64 output), double-buffered
// 6-plane LDS (2 x 72 KB = 144 KB, 1 block/CU). Stage for kt+1 issued at the
// top of kt's body. Verified 3x at 159-160us / MfmaUtil 59% / 0 conflicts.
// FROZEN.
// ---------------------------------------------------------------------------
__global__ __launch_bounds__(512, 2) void gemm_h_mfma(
        const unsigned short* __restrict__ Xh, const unsigned short* __restrict__ Xm,
        const unsigned short* __restrict__ Xl, const unsigned short* __restrict__ WTh,
        const unsigned short* __restrict__ WTm, const unsigned short* __restrict__ WTl,
        float* __restrict__ H) {
    const int K = I_, N = O_;
    __shared__ unsigned short P[2][36864];

    const int tid = threadIdx.x;
    const int lane = tid & 63;
    const int wid = tid >> 6;             // 0..7
    const int wrow = wid >> 2;            // 0..1 -> rows wrow*64
    const int wcol = wid & 3;             // 0..3 -> cols wcol*64
    const int l15 = lane & 15, quad = lane >> 4;
    const int bm = blockIdx.x * 128, bn = blockIdx.y * 256;

    const int srow = tid >> 2, sch = tid & 3;
    const int schg = sch ^ ((srow >> 1) & 3);
    const unsigned short* gsrcA[3];
    const unsigned short* gsrcB[3];
    gsrcA[0] = Xh  + (size_t)(bm + srow) * K + schg * 8;
    gsrcA[1] = Xm  + (size_t)(bm + srow) * K + schg * 8;
    gsrcA[2] = Xl  + (size_t)(bm + srow) * K + schg * 8;
    gsrcB[0] = WTh + (size_t)(bn + srow) * K + schg * 8;
    gsrcB[1] = WTm + (size_t)(bn + srow) * K + schg * 8;
    gsrcB[2] = WTl + (size_t)(bn + srow) * K + schg * 8;

    auto stage = [&](int kt) {
        unsigned short* wb = &P[0][0] + (size_t)(kt & 1) * 36864;
        const size_t k0 = (size_t)kt * 32;
#pragma unroll
        for (int p = 0; p < 3; ++p)
            gld_lds16(gsrcA[p] + k0, wb + p * 4096 + tid * 8);
#pragma unroll
        for (int p = 0; p < 3; ++p) {
            unsigned short* bb = wb + 12288 + p * 8192 + tid * 8;
            gld_lds16(gsrcB[p] + k0, bb);
            gld_lds16(gsrcB[p] + (size_t)128 * K + k0, bb + 4096);
        }
    };

    floatx4 acc[4][4];
#pragma unroll
    for (int mt = 0; mt < 4; ++mt)
#pragma unroll
        for (int nt = 0; nt < 4; ++nt) acc[mt][nt] = (floatx4)(0.f);

    stage(0);   // prologue

    for (int kt = 0; kt < 32; ++kt) {
        const unsigned short* rb = &P[0][0] + (size_t)(kt & 1) * 36864;

        asm volatile("" ::: "memory");
        __builtin_amdgcn_s_waitcnt(0x1F70);   // vmcnt(0), lgkm/exp no-wait
        __builtin_amdgcn_s_barrier();
        asm volatile("" ::: "memory");

        half8 Af[3][4];
#pragma unroll
        for (int pa = 0; pa < 3; ++pa)
#pragma unroll
            for (int mt = 0; mt < 4; ++mt) {
                const int row = wrow * 64 + mt * 16 + l15;
                const int chk = quad ^ ((row >> 1) & 3);
                Af[pa][mt] = *(const half8*)(rb + pa * 4096 + row * 32 + chk * 8);
            }

        if (kt < 31) stage(kt + 1);   // in flight across this step's MFMAs

#pragma unroll
        for (int pb = 0; pb < 3; ++pb) {
            half8 Bf[4];
#pragma unroll
            for (int nt = 0; nt < 4; ++nt) {
                const int col = wcol * 64 + nt * 16 + l15;
                const int chk = quad ^ ((col >> 1) & 3);
                Bf[nt] = *(const half8*)(rb + 12288 + pb * 8192 + col * 32 + chk * 8);
            }
#pragma unroll
            for (int nt = 0; nt < 4; ++nt)
#pragma unroll
                for (int mt = 0; mt < 4; ++mt) {
                    acc[mt][nt] = __builtin_amdgcn_mfma_f32_16x16x32_f16(Af[0][mt], Bf[nt], acc[mt][nt], 0, 0, 0);
                    if (pb < 2)
                        acc[mt][nt] = __builtin_amdgcn_mfma_f32_16x16x32_f16(Af[1][mt], Bf[nt], acc[mt][nt], 0, 0, 0);
                    if (pb == 0)
                        acc[mt][nt] = __builtin_amdgcn_mfma_f32_16x16x32_f16(Af[2][mt], Bf[nt], acc[mt][nt], 0, 0, 0);
                }
        }
    }

    // epilogue: C/D row = quad*4 + reg, col = lane&15
#pragma unroll
    for (int mt = 0; mt < 4; ++mt)
#pragma unroll
        for (int nt = 0; nt < 4; ++nt) {
            int grow = bm + wrow * 64 + mt * 16 + quad * 4;
            int gcol = bn + wcol * 64 + nt * 16 + l15;
            float* hp = H + (size_t)grow * N + gcol;
#pragma unroll
            for (int r = 0; r < 4; ++r) hp[(size_t)r * N] = acc[mt][nt][r];
        }
}

// ---------------------------------------------------------------------------
// d = w^T w   (fp32 exact-class, 256 blocks, ~25 us measured).
// ---------------------------------------------------------------------------
__global__ __launch_bounds__(256) void gemm_wtw(const float* __restrict__ W,
                                                float* __restrict__ D) {
    const int K = I_, N = O_;
    __shared__ float As[32][68];
    __shared__ float Bs[32][68];
    const int tid = threadIdx.x;
    const int tx = tid & 15, ty = tid >> 4;
    const int bj = blockIdx.x * 64, bo = blockIdx.y * 64;
    const int lr = tid >> 4;
    const int lc = (tid & 15) << 2;

    float acc[4][4];
#pragma unroll
    for (int m = 0; m < 4; m++)
#pragma unroll
        for (int n = 0; n < 4; n++) acc[m][n] = 0.f;

    for (int k0 = 0; k0 < K; k0 += 32) {
        float4 a0 = *(const float4*)(W + (size_t)(k0 + lr) * N + bj + lc);
        float4 a1 = *(const float4*)(W + (size_t)(k0 + lr + 16) * N + bj + lc);
        float4 b0 = *(const float4*)(W + (size_t)(k0 + lr) * N + bo + lc);
        float4 b1 = *(const float4*)(W + (size_t)(k0 + lr + 16) * N + bo + lc);
        __syncthreads();
        *(float4*)&As[lr][lc] = a0; *(float4*)&As[lr + 16][lc] = a1;
        *(float4*)&Bs[lr][lc] = b0; *(float4*)&Bs[lr + 16][lc] = b1;
        __syncthreads();
#pragma unroll
        for (int k = 0; k < 32; ++k) {
            float4 av = *(const float4*)&As[k][ty * 4];
            float4 bv = *(const float4*)&Bs[k][tx * 4];
            float am[4] = {av.x, av.y, av.z, av.w};
            float bb[4] = {bv.x, bv.y, bv.z, bv.w};
#pragma unroll
            for (int m = 0; m < 4; m++)
#pragma unroll
                for (int n = 0; n < 4; n++) acc[m][n] += am[m] * bb[n];
        }
    }
#pragma unroll
    for (int m = 0; m < 4; m++) {
        float4 v = make_float4(acc[m][0], acc[m][1], acc[m][2], acc[m][3]);
        *(float4*)(D + (size_t)(bj + ty * 4 + m) * N + bo + tx * 4) = v;
    }
}

// inv_norm[o] = 1/(d[o][o] + 1e-8); zero the spike counter; zero the dummy
// gather row (zrow, reused dead x_h region) used by the scan's padded batches.
__global__ void colnorm_diag(const float* __restrict__ D, float* __restrict__ invn,
                             unsigned int* __restrict__ counter,
                             float* __restrict__ zrow) {
    int o = blockIdx.x * 256 + threadIdx.x;
    if (o == 0) *counter = 0u;
    invn[o] = 1.0f / (D[(size_t)o * O_ + o] + 1e-8f);
    zrow[o] = 0.0f;
}

// ---------------------------------------------------------------------------
// Sequential scan, r8: 128 blocks x 512 threads (one sample/block, restored
// after r7's 2-samples/block lengthened the per-block chain — with idle CUs,
// wall time = per-block chain). ATOMIC-FREE SEGMENTED APPEND:
//  - wave w owns list segment lst[q][w*128 ..): slot = in-wave ballot prefix
//    (already computed) -> scatter write; lane 0 plain-stores cntW[q][w].
//    No LDS atomicAdd (was serializing 8 waves on one address), no shfl
//    broadcast.
//  - reader: two uniform int4 LDS reads give all 8 counts; register prefix
//    sums; gather index gi -> (segment, offset) via a 7-deep cndmask cascade
//    (pure VALU, overlaps the loads).
//  - gather in batches of 8 with zrow padding (exact +0.0).
// Summation order = segment-major ascending (fp32 reorder within the same
// exact class that has passed throughout).
// Race-safety: one LDS-only barrier per step; step-t writes -> [q=(t+1)&1],
// step-t reads <- [p=t&1] (disjoint buffers between consecutive barriers).
// ---------------------------------------------------------------------------
__global__ __launch_bounds__(512) void scan_kernel(const float* __restrict__ h,
                                                   const float* __restrict__ d,
                                                   const float* __restrict__ invn,
                                                   const float* __restrict__ bias,
                                                   const float* __restrict__ beta,
                                                   const float* __restrict__ zrow,
                                                   float* __restrict__ out,
                                                   unsigned int* __restrict__ spike_count) {
    __shared__ int lst[2][O_];          // segmented by wave: [w*128, w*128+128)
    __shared__ int cntW[2][8];
    __shared__ unsigned int red[512];

    const int tid = threadIdx.x;
    const int lane = tid & 63;
    const int w = tid >> 6;             // wave id 0..7
    const int b = blockIdx.x;
    const int o2 = tid * 2;
    const float betav = beta[0];
    const float omb = 1.0f - betav;

    const float2 invn2 = *(const float2*)(invn + o2);
    const float2 b2 = *(const float2*)(bias + o2);
    float2 mem2 = make_float2(0.f, 0.f);

    if (tid < 16) ((int*)cntW)[tid] = 0;
    unsigned int local_count = 0;
    const float* hb = h + (size_t)b * T_ * O_;
    float* ob = out + (size_t)b * T_ * O_;
    const float* zp = zrow + o2;
    const unsigned long long below = (lane == 63) ? 0xFFFFFFFFFFFFFFFFull >> 1
                                                  : ((1ull << lane) - 1ull);

    float2 hcur = *(const float2*)(hb + o2);   // t = 0
    __syncthreads();

    for (int t = 0; t < T_; ++t) {
        const int p = t & 1, q = p ^ 1;

        // all 8 segment counts: two uniform 16B LDS reads
        const int4 ca = *(const int4*)&cntW[p][0];
        const int4 cb = *(const int4*)&cntW[p][4];
        const int pf1 = ca.x;
        const int pf2 = pf1 + ca.y;
        const int pf3 = pf2 + ca.z;
        const int pf4 = pf3 + ca.w;
        const int pf5 = pf4 + cb.x;
        const int pf6 = pf5 + cb.y;
        const int pf7 = pf6 + cb.z;
        const int n   = pf7 + cb.w;
        // addr for gi in segment w is 128*w + (gi - pf_w)
        const int a1 = 128 * 1 - pf1, a2 = 128 * 2 - pf2, a3 = 128 * 3 - pf3;
        const int a4 = 128 * 4 - pf4, a5 = 128 * 5 - pf5, a6 = 128 * 6 - pf6;
        const int a7 = 128 * 7 - pf7;

        float2 hnext = make_float2(0.f, 0.f);
        if (t + 1 < T_) hnext = *(const float2*)(hb + (size_t)(t + 1) * O_ + o2);

        float2 rst = make_float2(0.f, 0.f);
        for (int i = 0; i < n; i += 8) {
            const float* src[8];
#pragma unroll
            for (int u = 0; u < 8; ++u) {
                const int gi = i + u;
                int addr = gi;
                addr = (gi >= pf1) ? gi + a1 : addr;
                addr = (gi >= pf2) ? gi + a2 : addr;
                addr = (gi >= pf3) ? gi + a3 : addr;
                addr = (gi >= pf4) ? gi + a4 : addr;
                addr = (gi >= pf5) ? gi + a5 : addr;
                addr = (gi >= pf6) ? gi + a6 : addr;
                addr = (gi >= pf7) ? gi + a7 : addr;
                const int j = lst[p][addr & (O_ - 1)];
                src[u] = (gi < n) ? (d + (size_t)j * O_ + o2) : zp;
            }
            float2 v[8];
#pragma unroll
            for (int u = 0; u < 8; ++u) v[u] = *(const float2*)src[u];
#pragma unroll
            for (int u = 0; u < 8; ++u) { rst.x += v[u].x; rst.y += v[u].y; }
        }

        mem2.x = (mem2.x - rst.x) * betav + hcur.x * omb;
        mem2.y = (mem2.y - rst.y) * betav + hcur.y * omb;

        const int s0 = (mem2.x * invn2.x - b2.x) > 0.0f;
        const int s1 = (mem2.y * invn2.y - b2.y) > 0.0f;

        *(float2*)(ob + (size_t)t * O_ + o2) =
            make_float2(s0 ? 1.f : 0.f, s1 ? 1.f : 0.f);
        local_count += (unsigned)(s0 + s1);

        // atomic-free segmented append into this wave's own slice
        const unsigned long long mk0 = __ballot(s0);
        const unsigned long long mk1 = __ballot(s1);
        const int c0 = __popcll(mk0);
        if (s0) lst[q][w * 128 + __popcll(mk0 & below)] = o2 + 0;
        if (s1) lst[q][w * 128 + c0 + __popcll(mk1 & below)] = o2 + 1;
        if (lane == 0) cntW[q][w] = c0 + __popcll(mk1);

        barrier_lds_only();
        hcur = hnext;
    }

    red[tid] = local_count;
    __syncthreads();
    for (int st = 256; st > 0; st >>= 1) {
        if (tid < st) red[tid] += red[tid + st];
        __syncthreads();
    }
    if (tid == 0) atomicAdd(spike_count, red[0]);
}

__global__ void finalize_loss(const unsigned int* __restrict__ spike_count,
                              float* __restrict__ loss_out) {
    *loss_out = 0.5f * ((float)(*spike_count) / 16777216.0f);
}

// ---------------------------------------------------------------------------
extern "C" void kernel_launch(void* const* d_in, const int* in_sizes, int n_in,
                              void* d_out, int out_size, void* d_ws, size_t ws_size,
                              hipStream_t stream) {
    const float* x    = (const float*)d_in[0];   // [B,T,I]
    const float* w    = (const float*)d_in[1];   // [I,O]
    const float* beta = (const float*)d_in[2];   // [1]
    const float* bias = (const float*)d_in[3];   // [O]
    float* out = (float*)d_out;                  // NOUT spikes + 1 loss

    // workspace layout (~170 MB)
    char* ws = (char*)d_ws;
    float* h    = (float*)ws;                                         // 64 MiB
    float* dmat = (float*)(ws + (size_t)67108864);                    // 4 MiB
    float* invn = (float*)(ws + (size_t)71303168);                    // 4 KiB
    unsigned int* cntp = (unsigned int*)(ws + (size_t)71307264);      // 4 KiB
    unsigned short* wt_h = (unsigned short*)(ws + (size_t)71311360);  // 2 MiB
    unsigned short* wt_m = (unsigned short*)(ws + (size_t)73408512);  // 2 MiB
    unsigned short* wt_l = (unsigned short*)(ws + (size_t)75505664);  // 2 MiB
    unsigned short* x_h  = (unsigned short*)(ws + (size_t)77602816);  // 32 MiB
    unsigned short* x_m  = (unsigned short*)(ws + (size_t)111157248); // 32 MiB
    unsigned short* x_l  = (unsigned short*)(ws + (size_t)144711680); // 32 MiB
    float* zrow = (float*)x_h;   // dead after gemm_h; zeroed by colnorm_diag

    split_x<<<M_ * I_ / 1024, 256, 0, stream>>>(x, x_h, x_m, x_l);
    split_wt<<<dim3(I_ / 64, O_ / 64), 256, 0, stream>>>(w, wt_h, wt_m, wt_l);
    gemm_h_mfma<<<dim3(M_ / 128, O_ / 256), 512, 0, stream>>>(x_h, x_m, x_l,
                                                              wt_h, wt_m, wt_l, h);
    gemm_wtw<<<dim3(O_ / 64, O_ / 64), 256, 0, stream>>>(w, dmat);
    colnorm_diag<<<O_ / 256, 256, 0, stream>>>(dmat, invn, cntp, zrow);
    scan_kernel<<<B_, 512, 0, stream>>>(h, dmat, invn, bias, beta, zrow, out, cntp);
    finalize_loss<<<1, 1, 0, stream>>>(cntp, out + (size_t)NOUT);
}

// Round 10
// 493.589 us; speedup vs baseline: 1.3082x; 1.0517x over previous
//
#include <hip/hip_runtime.h>
#include <hip/hip_fp16.h>

#define B_ 128
#define T_ 128
#define I_ 1024
#define O_ 1024
#define M_ (B_*T_)          // 16384 rows of h
#define NOUT (M_*O_)        // 16777216 spike outputs, loss at index NOUT

typedef __attribute__((ext_vector_type(8))) _Float16 half8;  // 8 fp16 = 4 VGPR
typedef __attribute__((ext_vector_type(4))) float floatx4;   // MFMA acc

// async global->LDS, 16B per lane. LDS dest = wave-uniform base + lane*16.
__device__ __forceinline__ void gld_lds16(const void* g, void* l) {
    __builtin_amdgcn_global_load_lds((const __attribute__((address_space(1))) void*)g,
                                     (__attribute__((address_space(3))) void*)l,
                                     16, 0, 0);
}

// Workgroup barrier that waits ONLY on LDS ops (lgkmcnt(0)); does NOT drain
// vmcnt. 0xC07F = vmcnt 63 (bits 3:0 & 15:14), expcnt 7, lgkmcnt 0.
__device__ __forceinline__ void barrier_lds_only() {
    asm volatile("" ::: "memory");
    __builtin_amdgcn_s_waitcnt(0xC07F);
    __builtin_amdgcn_s_barrier();
    asm volatile("" ::: "memory");
}

// Exact 3-way FP16 split: x = h + m + l + r with |r| <~ max(2^-33|x|, 2^-26).
// 6 kept cross-products (hh, hm, mh, mm, hl, lh) carry everything down to
// 2^-22 relative; dropped terms (ml, lm, ll) are <= 2^-33.
__device__ __forceinline__ void split3h(float x, unsigned short& h,
                                        unsigned short& m, unsigned short& l) {
    __half f0 = __float2half(x);
    float r1 = x - __half2float(f0);
    __half f1 = __float2half(r1);
    float r2 = r1 - __half2float(f1);
    __half f2 = __float2half(r2);
    h = __half_as_ushort(f0);
    m = __half_as_ushort(f1);
    l = __half_as_ushort(f2);
}

// ---------------------------------------------------------------------------
// FUSED split kernel: blocks [0, 16384) run the split_x path; blocks
// [16384, 16640) run the split_wt transpose path. One launch instead of two.
// ---------------------------------------------------------------------------
__global__ __launch_bounds__(256) void split_fused(
        const float* __restrict__ X, unsigned short* __restrict__ Xh,
        unsigned short* __restrict__ Xm, unsigned short* __restrict__ Xl,
        const float* __restrict__ W, unsigned short* __restrict__ WTh,
        unsigned short* __restrict__ WTm, unsigned short* __restrict__ WTl) {
    __shared__ float t[64][65];
    const int tid = threadIdx.x;

    if (blockIdx.x < 16384) {
        // ---- split_x: x [M,K] f32 -> 3 fp16 planes, same layout ----
        size_t base = ((size_t)blockIdx.x * 256 + tid) * 4;
        float4 v = *(const float4*)(X + base);
        ushort4 hh, mm, ll;
        split3h(v.x, hh.x, mm.x, ll.x);
        split3h(v.y, hh.y, mm.y, ll.y);
        split3h(v.z, hh.z, mm.z, ll.z);
        split3h(v.w, hh.w, mm.w, ll.w);
        *(ushort4*)(Xh + base) = hh;
        *(ushort4*)(Xm + base) = mm;
        *(ushort4*)(Xl + base) = ll;
        return;
    }

    // ---- split_wt: w [K][N] f32 -> three TRANSPOSED fp16 planes [N][K] ----
    const int bx = blockIdx.x - 16384;          // 0..255
    const int r0 = (bx & 15) * 64;              // I-dim tile
    const int c0 = (bx >> 4) * 64;              // O-dim tile
    const int tx = tid & 63, ty4 = tid >> 6;
#pragma unroll
    for (int j = 0; j < 16; ++j) {
        int row = j * 4 + ty4;
        t[row][tx] = W[(size_t)(r0 + row) * O_ + c0 + tx];
    }
    __syncthreads();
#pragma unroll
    for (int j = 0; j < 16; ++j) {
        int i = j * 4 + ty4;
        float v = t[tx][i];
        unsigned short h, m, l;
        split3h(v, h, m, l);
        size_t off = (size_t)(c0 + i) * I_ + r0 + tx;
        WTh[off] = h; WTm[off] = m; WTl[off] = l;
    }
}

// ---------------------------------------------------------------------------
// h = x @ w, fp16 3-way-split MFMA, 6 of 9 plane products (hh,hm,mh,mm,hl,lh).
// 128x256 tile, 512 threads, 8 waves x (64x64 output), double-buffered
// 6-plane LDS (2 x 72 KB = 144 KB, 1 block/CU). Stage for kt+1 issued at the
// top of kt's body. Verified 4x at 159-160us / MfmaUtil 59% / 0 conflicts.
// FROZEN.
// ---------------------------------------------------------------------------
__global__ __launch_bounds__(512, 2) void gemm_h_mfma(
        const unsigned short* __restrict__ Xh, const unsigned short* __restrict__ Xm,
        const unsigned short* __restrict__ Xl, const unsigned short* __restrict__ WTh,
        const unsigned short* __restrict__ WTm, const unsigned short* __restrict__ WTl,
        float* __restrict__ H) {
    const int K = I_, N = O_;
    __shared__ unsigned short P[2][36864];

    const int tid = threadIdx.x;
    const int lane = tid & 63;
    const int wid = tid >> 6;             // 0..7
    const int wrow = wid >> 2;            // 0..1 -> rows wrow*64
    const int wcol = wid & 3;             // 0..3 -> cols wcol*64
    const int l15 = lane & 15, quad = lane >> 4;
    const int bm = blockIdx.x * 128, bn = blockIdx.y * 256;

    const int srow = tid >> 2, sch = tid & 3;
    const int schg = sch ^ ((srow >> 1) & 3);
    const unsigned short* gsrcA[3];
    const unsigned short* gsrcB[3];
    gsrcA[0] = Xh  + (size_t)(bm + srow) * K + schg * 8;
    gsrcA[1] = Xm  + (size_t)(bm + srow) * K + schg * 8;
    gsrcA[2] = Xl  + (size_t)(bm + srow) * K + schg * 8;
    gsrcB[0] = WTh + (size_t)(bn + srow) * K + schg * 8;
    gsrcB[1] = WTm + (size_t)(bn + srow) * K + schg * 8;
    gsrcB[2] = WTl + (size_t)(bn + srow) * K + schg * 8;

    auto stage = [&](int kt) {
        unsigned short* wb = &P[0][0] + (size_t)(kt & 1) * 36864;
        const size_t k0 = (size_t)kt * 32;
#pragma unroll
        for (int p = 0; p < 3; ++p)
            gld_lds16(gsrcA[p] + k0, wb + p * 4096 + tid * 8);
#pragma unroll
        for (int p = 0; p < 3; ++p) {
            unsigned short* bb = wb + 12288 + p * 8192 + tid * 8;
            gld_lds16(gsrcB[p] + k0, bb);
            gld_lds16(gsrcB[p] + (size_t)128 * K + k0, bb + 4096);
        }
    };

    floatx4 acc[4][4];
#pragma unroll
    for (int mt = 0; mt < 4; ++mt)
#pragma unroll
        for (int nt = 0; nt < 4; ++nt) acc[mt][nt] = (floatx4)(0.f);

    stage(0);   // prologue

    for (int kt = 0; kt < 32; ++kt) {
        const unsigned short* rb = &P[0][0] + (size_t)(kt & 1) * 36864;

        asm volatile("" ::: "memory");
        __builtin_amdgcn_s_waitcnt(0x1F70);   // vmcnt(0), lgkm/exp no-wait
        __builtin_amdgcn_s_barrier();
        asm volatile("" ::: "memory");

        half8 Af[3][4];
#pragma unroll
        for (int pa = 0; pa < 3; ++pa)
#pragma unroll
            for (int mt = 0; mt < 4; ++mt) {
                const int row = wrow * 64 + mt * 16 + l15;
                const int chk = quad ^ ((row >> 1) & 3);
                Af[pa][mt] = *(const half8*)(rb + pa * 4096 + row * 32 + chk * 8);
            }

        if (kt < 31) stage(kt + 1);   // in flight across this step's MFMAs

#pragma unroll
        for (int pb = 0; pb < 3; ++pb) {
            half8 Bf[4];
#pragma unroll
            for (int nt = 0; nt < 4; ++nt) {
                const int col = wcol * 64 + nt * 16 + l15;
                const int chk = quad ^ ((col >> 1) & 3);
                Bf[nt] = *(const half8*)(rb + 12288 + pb * 8192 + col * 32 + chk * 8);
            }
#pragma unroll
            for (int nt = 0; nt < 4; ++nt)
#pragma unroll
                for (int mt = 0; mt < 4; ++mt) {
                    acc[mt][nt] = __builtin_amdgcn_mfma_f32_16x16x32_f16(Af[0][mt], Bf[nt], acc[mt][nt], 0, 0, 0);
                    if (pb < 2)
                        acc[mt][nt] = __builtin_amdgcn_mfma_f32_16x16x32_f16(Af[1][mt], Bf[nt], acc[mt][nt], 0, 0, 0);
                    if (pb == 0)
                        acc[mt][nt] = __builtin_amdgcn_mfma_f32_16x16x32_f16(Af[2][mt], Bf[nt], acc[mt][nt], 0, 0, 0);
                }
        }
    }

    // epilogue: C/D row = quad*4 + reg, col = lane&15
#pragma unroll
    for (int mt = 0; mt < 4; ++mt)
#pragma unroll
        for (int nt = 0; nt < 4; ++nt) {
            int grow = bm + wrow * 64 + mt * 16 + quad * 4;
            int gcol = bn + wcol * 64 + nt * 16 + l15;
            float* hp = H + (size_t)grow * N + gcol;
#pragma unroll
            for (int r = 0; r < 4; ++r) hp[(size_t)r * N] = acc[mt][nt][r];
        }
}

// ---------------------------------------------------------------------------
// d = w^T w (fp32 exact-class, 256 blocks, ~25 us). colnorm FUSED into the
// epilogue — diagonal blocks (bj==bo) write invn from their diagonal
// accumulators (threads tx==ty own them); block (0,0) also zeroes the spike
// counter and the scan's zero-pad row. Stream order guarantees: runs after
// gemm_h (so overwriting the x_h region with zrow is safe) and before scan.
// ---------------------------------------------------------------------------
__global__ __launch_bounds__(256) void gemm_wtw(const float* __restrict__ W,
                                                float* __restrict__ D,
                                                float* __restrict__ invn,
                                                unsigned int* __restrict__ counter,
                                                float* __restrict__ zrow) {
    const int K = I_, N = O_;
    __shared__ float As[32][68];
    __shared__ float Bs[32][68];
    const int tid = threadIdx.x;
    const int tx = tid & 15, ty = tid >> 4;
    const int bj = blockIdx.x * 64, bo = blockIdx.y * 64;
    const int lr = tid >> 4;
    const int lc = (tid & 15) << 2;

    float acc[4][4];
#pragma unroll
    for (int m = 0; m < 4; m++)
#pragma unroll
        for (int n = 0; n < 4; n++) acc[m][n] = 0.f;

    for (int k0 = 0; k0 < K; k0 += 32) {
        float4 a0 = *(const float4*)(W + (size_t)(k0 + lr) * N + bj + lc);
        float4 a1 = *(const float4*)(W + (size_t)(k0 + lr + 16) * N + bj + lc);
        float4 b0 = *(const float4*)(W + (size_t)(k0 + lr) * N + bo + lc);
        float4 b1 = *(const float4*)(W + (size_t)(k0 + lr + 16) * N + bo + lc);
        __syncthreads();
        *(float4*)&As[lr][lc] = a0; *(float4*)&As[lr + 16][lc] = a1;
        *(float4*)&Bs[lr][lc] = b0; *(float4*)&Bs[lr + 16][lc] = b1;
        __syncthreads();
#pragma unroll
        for (int k = 0; k < 32; ++k) {
            float4 av = *(const float4*)&As[k][ty * 4];
            float4 bv = *(const float4*)&Bs[k][tx * 4];
            float am[4] = {av.x, av.y, av.z, av.w};
            float bb[4] = {bv.x, bv.y, bv.z, bv.w};
#pragma unroll
            for (int m = 0; m < 4; m++)
#pragma unroll
                for (int n = 0; n < 4; n++) acc[m][n] += am[m] * bb[n];
        }
    }
#pragma unroll
    for (int m = 0; m < 4; m++) {
        float4 v = make_float4(acc[m][0], acc[m][1], acc[m][2], acc[m][3]);
        *(float4*)(D + (size_t)(bj + ty * 4 + m) * N + bo + tx * 4) = v;
    }

    // fused colnorm: diagonal blocks write invn; block (0,0) zeroes extras
    if (bj == bo) {
        if (tx == ty) {
#pragma unroll
            for (int m = 0; m < 4; m++)
                invn[bj + ty * 4 + m] = 1.0f / (acc[m][m] + 1e-8f);
        }
        if (bj == 0) {
            if (tid == 0) *counter = 0u;
            *(float4*)(zrow + tid * 4) = make_float4(0.f, 0.f, 0.f, 0.f);
        }
    }
}

// ---------------------------------------------------------------------------
// Sequential scan — EXACT r5 version (measured ~155 us, the best of the five
// protocol variants tried in r5-r8): 512 threads/block, one sample/block,
// thread owns 2 contiguous neurons. ONE LDS-only barrier per step;
// ballot-aggregated appends with a single lane-0 LDS atomicAdd + shfl per
// wave; d-row gather in 8-batches with reader-side zero-row padding.
// r8 lesson: the "atomic-free" segmented variant register-starved the gather
// (VGPR 24) and serialized the loads -> 208 us. Do not restructure further.
// Race-safety: barrier every step; step-t appends -> lst[(t+1)&1], step-t
// reads <- lst[t&1] (disjoint between consecutive barriers).
// ---------------------------------------------------------------------------
__global__ __launch_bounds__(512) void scan_kernel(const float* __restrict__ h,
                                                   const float* __restrict__ d,
                                                   const float* __restrict__ invn,
                                                   const float* __restrict__ bias,
                                                   const float* __restrict__ beta,
                                                   const float* __restrict__ zrow,
                                                   float* __restrict__ out,
                                                   unsigned int* __restrict__ spike_count) {
    __shared__ int lst[2][O_];
    __shared__ int cnt[T_ + 1];
    __shared__ unsigned int red[512];

    const int tid = threadIdx.x;
    const int lane = tid & 63;
    const int b = blockIdx.x;
    const int o2 = tid * 2;
    const float betav = beta[0];
    const float omb = 1.0f - betav;

    const float2 invn2 = *(const float2*)(invn + o2);
    const float2 b2 = *(const float2*)(bias + o2);
    float2 mem2 = make_float2(0.f, 0.f);

    for (int i = tid; i <= T_; i += 512) cnt[i] = 0;
    unsigned int local_count = 0;
    const float* hb = h + (size_t)b * T_ * O_;
    float* ob = out + (size_t)b * T_ * O_;
    const float* zp = zrow + o2;
    const unsigned long long below = (lane == 63) ? 0xFFFFFFFFFFFFFFFFull >> 1
                                                  : ((1ull << lane) - 1ull);

    float2 hcur = *(const float2*)(hb + o2);   // t = 0
    __syncthreads();

    for (int t = 0; t < T_; ++t) {
        const int p = t & 1, q = p ^ 1;
        const int n = cnt[t];

        float2 hnext = make_float2(0.f, 0.f);
        if (t + 1 < T_) hnext = *(const float2*)(hb + (size_t)(t + 1) * O_ + o2);

        float2 rst = make_float2(0.f, 0.f);
        for (int i = 0; i < n; i += 8) {
            const float* src[8];
#pragma unroll
            for (int u = 0; u < 8; ++u) {
                const int idx = i + u;
                const int j = lst[p][idx & (O_ - 1)];   // in-bounds read; value
                                                        // only used when idx<n
                src[u] = (idx < n) ? (d + (size_t)j * O_ + o2) : zp;
            }
            float2 v[8];
#pragma unroll
            for (int u = 0; u < 8; ++u) v[u] = *(const float2*)src[u];
#pragma unroll
            for (int u = 0; u < 8; ++u) { rst.x += v[u].x; rst.y += v[u].y; }
        }

        mem2.x = (mem2.x - rst.x) * betav + hcur.x * omb;
        mem2.y = (mem2.y - rst.y) * betav + hcur.y * omb;

        const int s0 = (mem2.x * invn2.x - b2.x) > 0.0f;
        const int s1 = (mem2.y * invn2.y - b2.y) > 0.0f;

        *(float2*)(ob + (size_t)t * O_ + o2) =
            make_float2(s0 ? 1.f : 0.f, s1 ? 1.f : 0.f);
        local_count += (unsigned)(s0 + s1);

        // ballot-aggregated appends into lst[q] / cnt[t+1]: ONE atomic per wave
        unsigned long long mk0 = __ballot(s0);
        unsigned long long mk1 = __ballot(s1);
        const int c0 = __popcll(mk0);
        const int tot = c0 + __popcll(mk1);
        int base = 0;
        if (lane == 0 && tot) base = atomicAdd(&cnt[t + 1], tot);
        base = __shfl(base, 0, 64);
        if (s0) lst[q][base + __popcll(mk0 & below)] = o2 + 0;
        base += c0;
        if (s1) lst[q][base + __popcll(mk1 & below)] = o2 + 1;

        barrier_lds_only();
        hcur = hnext;
    }

    red[tid] = local_count;
    __syncthreads();
    for (int st = 256; st > 0; st >>= 1) {
        if (tid < st) red[tid] += red[tid + st];
        __syncthreads();
    }
    if (tid == 0) atomicAdd(spike_count, red[0]);
}

__global__ void finalize_loss(const unsigned int* __restrict__ spike_count,
                              float* __restrict__ loss_out) {
    *loss_out = 0.5f * ((float)(*spike_count) / 16777216.0f);
}

// ---------------------------------------------------------------------------
extern "C" void kernel_launch(void* const* d_in, const int* in_sizes, int n_in,
                              void* d_out, int out_size, void* d_ws, size_t ws_size,
                              hipStream_t stream) {
    const float* x    = (const float*)d_in[0];   // [B,T,I]
    const float* w    = (const float*)d_in[1];   // [I,O]
    const float* beta = (const float*)d_in[2];   // [1]
    const float* bias = (const float*)d_in[3];   // [O]
    float* out = (float*)d_out;                  // NOUT spikes + 1 loss

    // workspace layout (~170 MB)
    char* ws = (char*)d_ws;
    float* h    = (float*)ws;                                         // 64 MiB
    float* dmat = (float*)(ws + (size_t)67108864);                    // 4 MiB
    float* invn = (float*)(ws + (size_t)71303168);                    // 4 KiB
    unsigned int* cntp = (unsigned int*)(ws + (size_t)71307264);      // 4 KiB
    unsigned short* wt_h = (unsigned short*)(ws + (size_t)71311360);  // 2 MiB
    unsigned short* wt_m = (unsigned short*)(ws + (size_t)73408512);  // 2 MiB
    unsigned short* wt_l = (unsigned short*)(ws + (size_t)75505664);  // 2 MiB
    unsigned short* x_h  = (unsigned short*)(ws + (size_t)77602816);  // 32 MiB
    unsigned short* x_m  = (unsigned short*)(ws + (size_t)111157248); // 32 MiB
    unsigned short* x_l  = (unsigned short*)(ws + (size_t)144711680); // 32 MiB
    float* zrow = (float*)x_h;   // dead after gemm_h; zeroed by gemm_wtw

    split_fused<<<16384 + 256, 256, 0, stream>>>(x, x_h, x_m, x_l,
                                                 w, wt_h, wt_m, wt_l);
    gemm_h_mfma<<<dim3(M_ / 128, O_ / 256), 512, 0, stream>>>(x_h, x_m, x_l,
                                                              wt_h, wt_m, wt_l, h);
    gemm_wtw<<<dim3(O_ / 64, O_ / 64), 256, 0, stream>>>(w, dmat, invn, cntp, zrow);
    scan_kernel<<<B_, 512, 0, stream>>>(h, dmat, invn, bias, beta, zrow, out, cntp);
    finalize_loss<<<1, 1, 0, stream>>>(cntp, out + (size_t)NOUT);
}

// Round 11
// 485.001 us; speedup vs baseline: 1.3314x; 1.0177x over previous
//
#include <hip/hip_runtime.h>
#include <hip/hip_fp16.h>

#define B_ 128
#define T_ 128
#define I_ 1024
#define O_ 1024
#define M_ (B_*T_)          // 16384 rows of h
#define NOUT (M_*O_)        // 16777216 spike outputs, loss at index NOUT

typedef __attribute__((ext_vector_type(8))) _Float16 half8;  // 8 fp16 = 4 VGPR
typedef __attribute__((ext_vector_type(4))) float floatx4;   // MFMA acc

// async global->LDS, 16B per lane. LDS dest = wave-uniform base + lane*16.
__device__ __forceinline__ void gld_lds16(const void* g, void* l) {
    __builtin_amdgcn_global_load_lds((const __attribute__((address_space(1))) void*)g,
                                     (__attribute__((address_space(3))) void*)l,
                                     16, 0, 0);
}

// Workgroup barrier that waits ONLY on LDS ops (lgkmcnt(0)); does NOT drain
// vmcnt. 0xC07F = vmcnt 63 (bits 3:0 & 15:14), expcnt 7, lgkmcnt 0.
__device__ __forceinline__ void barrier_lds_only() {
    asm volatile("" ::: "memory");
    __builtin_amdgcn_s_waitcnt(0xC07F);
    __builtin_amdgcn_s_barrier();
    asm volatile("" ::: "memory");
}

// Exact 3-way FP16 split: x = h + m + l + r with |r| <~ max(2^-33|x|, 2^-26).
// 6 kept cross-products (hh, hm, mh, mm, hl, lh) carry everything down to
// 2^-22 relative; dropped terms (ml, lm, ll) are <= 2^-33.
__device__ __forceinline__ void split3h(float x, unsigned short& h,
                                        unsigned short& m, unsigned short& l) {
    __half f0 = __float2half(x);
    float r1 = x - __half2float(f0);
    __half f1 = __float2half(r1);
    float r2 = r1 - __half2float(f1);
    __half f2 = __float2half(r2);
    h = __half_as_ushort(f0);
    m = __half_as_ushort(f1);
    l = __half_as_ushort(f2);
}

// ---------------------------------------------------------------------------
// FUSED split kernel: blocks [0, 16384) run the split_x path; blocks
// [16384, 16640) run the split_wt transpose path.
// ---------------------------------------------------------------------------
__global__ __launch_bounds__(256) void split_fused(
        const float* __restrict__ X, unsigned short* __restrict__ Xh,
        unsigned short* __restrict__ Xm, unsigned short* __restrict__ Xl,
        const float* __restrict__ W, unsigned short* __restrict__ WTh,
        unsigned short* __restrict__ WTm, unsigned short* __restrict__ WTl) {
    __shared__ float t[64][65];
    const int tid = threadIdx.x;

    if (blockIdx.x < 16384) {
        // ---- split_x: x [M,K] f32 -> 3 fp16 planes, same layout ----
        size_t base = ((size_t)blockIdx.x * 256 + tid) * 4;
        float4 v = *(const float4*)(X + base);
        ushort4 hh, mm, ll;
        split3h(v.x, hh.x, mm.x, ll.x);
        split3h(v.y, hh.y, mm.y, ll.y);
        split3h(v.z, hh.z, mm.z, ll.z);
        split3h(v.w, hh.w, mm.w, ll.w);
        *(ushort4*)(Xh + base) = hh;
        *(ushort4*)(Xm + base) = mm;
        *(ushort4*)(Xl + base) = ll;
        return;
    }

    // ---- split_wt: w [K][N] f32 -> three TRANSPOSED fp16 planes [N][K] ----
    const int bx = blockIdx.x - 16384;          // 0..255
    const int r0 = (bx & 15) * 64;              // I-dim tile
    const int c0 = (bx >> 4) * 64;              // O-dim tile
    const int tx = tid & 63, ty4 = tid >> 6;
#pragma unroll
    for (int j = 0; j < 16; ++j) {
        int row = j * 4 + ty4;
        t[row][tx] = W[(size_t)(r0 + row) * O_ + c0 + tx];
    }
    __syncthreads();
#pragma unroll
    for (int j = 0; j < 16; ++j) {
        int i = j * 4 + ty4;
        float v = t[tx][i];
        unsigned short h, m, l;
        split3h(v, h, m, l);
        size_t off = (size_t)(c0 + i) * I_ + r0 + tx;
        WTh[off] = h; WTm[off] = m; WTl[off] = l;
    }
}

// ---------------------------------------------------------------------------
// h = x @ w, fp16 3-way-split MFMA, 6 of 9 plane products (hh,hm,mh,mm,hl,lh).
// 128x256 tile, 512 threads, 8 waves x (64x64 output), double-buffered
// 6-plane LDS (2 x 72 KB = 144 KB, 1 block/CU). Stage for kt+1 issued at the
// top of kt's body. Verified 5x at 159-160us / MfmaUtil 59% / 0 conflicts.
// FROZEN.
// ---------------------------------------------------------------------------
__global__ __launch_bounds__(512, 2) void gemm_h_mfma(
        const unsigned short* __restrict__ Xh, const unsigned short* __restrict__ Xm,
        const unsigned short* __restrict__ Xl, const unsigned short* __restrict__ WTh,
        const unsigned short* __restrict__ WTm, const unsigned short* __restrict__ WTl,
        float* __restrict__ H) {
    const int K = I_, N = O_;
    __shared__ unsigned short P[2][36864];

    const int tid = threadIdx.x;
    const int lane = tid & 63;
    const int wid = tid >> 6;             // 0..7
    const int wrow = wid >> 2;            // 0..1 -> rows wrow*64
    const int wcol = wid & 3;             // 0..3 -> cols wcol*64
    const int l15 = lane & 15, quad = lane >> 4;
    const int bm = blockIdx.x * 128, bn = blockIdx.y * 256;

    const int srow = tid >> 2, sch = tid & 3;
    const int schg = sch ^ ((srow >> 1) & 3);
    const unsigned short* gsrcA[3];
    const unsigned short* gsrcB[3];
    gsrcA[0] = Xh  + (size_t)(bm + srow) * K + schg * 8;
    gsrcA[1] = Xm  + (size_t)(bm + srow) * K + schg * 8;
    gsrcA[2] = Xl  + (size_t)(bm + srow) * K + schg * 8;
    gsrcB[0] = WTh + (size_t)(bn + srow) * K + schg * 8;
    gsrcB[1] = WTm + (size_t)(bn + srow) * K + schg * 8;
    gsrcB[2] = WTl + (size_t)(bn + srow) * K + schg * 8;

    auto stage = [&](int kt) {
        unsigned short* wb = &P[0][0] + (size_t)(kt & 1) * 36864;
        const size_t k0 = (size_t)kt * 32;
#pragma unroll
        for (int p = 0; p < 3; ++p)
            gld_lds16(gsrcA[p] + k0, wb + p * 4096 + tid * 8);
#pragma unroll
        for (int p = 0; p < 3; ++p) {
            unsigned short* bb = wb + 12288 + p * 8192 + tid * 8;
            gld_lds16(gsrcB[p] + k0, bb);
            gld_lds16(gsrcB[p] + (size_t)128 * K + k0, bb + 4096);
        }
    };

    floatx4 acc[4][4];
#pragma unroll
    for (int mt = 0; mt < 4; ++mt)
#pragma unroll
        for (int nt = 0; nt < 4; ++nt) acc[mt][nt] = (floatx4)(0.f);

    stage(0);   // prologue

    for (int kt = 0; kt < 32; ++kt) {
        const unsigned short* rb = &P[0][0] + (size_t)(kt & 1) * 36864;

        asm volatile("" ::: "memory");
        __builtin_amdgcn_s_waitcnt(0x1F70);   // vmcnt(0), lgkm/exp no-wait
        __builtin_amdgcn_s_barrier();
        asm volatile("" ::: "memory");

        half8 Af[3][4];
#pragma unroll
        for (int pa = 0; pa < 3; ++pa)
#pragma unroll
            for (int mt = 0; mt < 4; ++mt) {
                const int row = wrow * 64 + mt * 16 + l15;
                const int chk = quad ^ ((row >> 1) & 3);
                Af[pa][mt] = *(const half8*)(rb + pa * 4096 + row * 32 + chk * 8);
            }

        if (kt < 31) stage(kt + 1);   // in flight across this step's MFMAs

#pragma unroll
        for (int pb = 0; pb < 3; ++pb) {
            half8 Bf[4];
#pragma unroll
            for (int nt = 0; nt < 4; ++nt) {
                const int col = wcol * 64 + nt * 16 + l15;
                const int chk = quad ^ ((col >> 1) & 3);
                Bf[nt] = *(const half8*)(rb + 12288 + pb * 8192 + col * 32 + chk * 8);
            }
#pragma unroll
            for (int nt = 0; nt < 4; ++nt)
#pragma unroll
                for (int mt = 0; mt < 4; ++mt) {
                    acc[mt][nt] = __builtin_amdgcn_mfma_f32_16x16x32_f16(Af[0][mt], Bf[nt], acc[mt][nt], 0, 0, 0);
                    if (pb < 2)
                        acc[mt][nt] = __builtin_amdgcn_mfma_f32_16x16x32_f16(Af[1][mt], Bf[nt], acc[mt][nt], 0, 0, 0);
                    if (pb == 0)
                        acc[mt][nt] = __builtin_amdgcn_mfma_f32_16x16x32_f16(Af[2][mt], Bf[nt], acc[mt][nt], 0, 0, 0);
                }
        }
    }

    // epilogue: C/D row = quad*4 + reg, col = lane&15
#pragma unroll
    for (int mt = 0; mt < 4; ++mt)
#pragma unroll
        for (int nt = 0; nt < 4; ++nt) {
            int grow = bm + wrow * 64 + mt * 16 + quad * 4;
            int gcol = bn + wcol * 64 + nt * 16 + l15;
            float* hp = H + (size_t)grow * N + gcol;
#pragma unroll
            for (int r = 0; r < 4; ++r) hp[(size_t)r * N] = acc[mt][nt][r];
        }
}

// ---------------------------------------------------------------------------
// d = w^T w (fp32 exact-class, 256 blocks, ~25 us). colnorm fused into the
// epilogue — diagonal blocks (bj==bo) write invn from their diagonal
// accumulators; block (0,0) also zeroes the spike counter and zrow.
// ---------------------------------------------------------------------------
__global__ __launch_bounds__(256) void gemm_wtw(const float* __restrict__ W,
                                                float* __restrict__ D,
                                                float* __restrict__ invn,
                                                unsigned int* __restrict__ counter,
                                                float* __restrict__ zrow) {
    const int K = I_, N = O_;
    __shared__ float As[32][68];
    __shared__ float Bs[32][68];
    const int tid = threadIdx.x;
    const int tx = tid & 15, ty = tid >> 4;
    const int bj = blockIdx.x * 64, bo = blockIdx.y * 64;
    const int lr = tid >> 4;
    const int lc = (tid & 15) << 2;

    float acc[4][4];
#pragma unroll
    for (int m = 0; m < 4; m++)
#pragma unroll
        for (int n = 0; n < 4; n++) acc[m][n] = 0.f;

    for (int k0 = 0; k0 < K; k0 += 32) {
        float4 a0 = *(const float4*)(W + (size_t)(k0 + lr) * N + bj + lc);
        float4 a1 = *(const float4*)(W + (size_t)(k0 + lr + 16) * N + bj + lc);
        float4 b0 = *(const float4*)(W + (size_t)(k0 + lr) * N + bo + lc);
        float4 b1 = *(const float4*)(W + (size_t)(k0 + lr + 16) * N + bo + lc);
        __syncthreads();
        *(float4*)&As[lr][lc] = a0; *(float4*)&As[lr + 16][lc] = a1;
        *(float4*)&Bs[lr][lc] = b0; *(float4*)&Bs[lr + 16][lc] = b1;
        __syncthreads();
#pragma unroll
        for (int k = 0; k < 32; ++k) {
            float4 av = *(const float4*)&As[k][ty * 4];
            float4 bv = *(const float4*)&Bs[k][tx * 4];
            float am[4] = {av.x, av.y, av.z, av.w};
            float bb[4] = {bv.x, bv.y, bv.z, bv.w};
#pragma unroll
            for (int m = 0; m < 4; m++)
#pragma unroll
                for (int n = 0; n < 4; n++) acc[m][n] += am[m] * bb[n];
        }
    }
#pragma unroll
    for (int m = 0; m < 4; m++) {
        float4 v = make_float4(acc[m][0], acc[m][1], acc[m][2], acc[m][3]);
        *(float4*)(D + (size_t)(bj + ty * 4 + m) * N + bo + tx * 4) = v;
    }

    // fused colnorm: diagonal blocks write invn; block (0,0) zeroes extras
    if (bj == bo) {
        if (tx == ty) {
#pragma unroll
            for (int m = 0; m < 4; m++)
                invn[bj + ty * 4 + m] = 1.0f / (acc[m][m] + 1e-8f);
        }
        if (bj == 0) {
            if (tid == 0) *counter = 0u;
            *(float4*)(zrow + tid * 4) = make_float4(0.f, 0.f, 0.f, 0.f);
        }
    }
}

// ---------------------------------------------------------------------------
// Sequential scan — r5 protocol (the measured best of five variants), with
// r11 codegen fixes for the VGPR-starvation the r10 counters exposed
// (VGPR_Count 24 -> serialized gather, 173us vs r5's <159us):
//  - __launch_bounds__(512, 1): occupancy target 1 wave/EU -> register
//    allocator may keep the whole 8-wide gather batch in flight. Occupancy
//    is grid-limited anyway (128 blocks on 256 CUs), so nothing is lost.
//  - gather addressing = uniform d base (SGPR pair) + 32-bit BYTE offsets
//    (one VGPR per in-flight load instead of a 64-bit pointer pair); the
//    zrow pad is an offset select (same workspace allocation, diff ~10.5MB).
// Protocol unchanged: one LDS-only barrier per step; ballot-aggregated
// appends, single lane-0 LDS atomicAdd + shfl per wave; 8-batch gather with
// zero-row padding (exact +0.0).
// Race-safety: barrier every step; step-t appends -> lst[(t+1)&1], step-t
// reads <- lst[t&1] (disjoint between consecutive barriers).
// ---------------------------------------------------------------------------
__global__ __launch_bounds__(512, 1) void scan_kernel(const float* __restrict__ h,
                                                      const float* __restrict__ d,
                                                      const float* __restrict__ invn,
                                                      const float* __restrict__ bias,
                                                      const float* __restrict__ beta,
                                                      const float* __restrict__ zrow,
                                                      float* __restrict__ out,
                                                      unsigned int* __restrict__ spike_count) {
    __shared__ int lst[2][O_];
    __shared__ int cnt[T_ + 1];
    __shared__ unsigned int red[512];

    const int tid = threadIdx.x;
    const int lane = tid & 63;
    const int b = blockIdx.x;
    const int o2 = tid * 2;
    const float betav = beta[0];
    const float omb = 1.0f - betav;

    const float2 invn2 = *(const float2*)(invn + o2);
    const float2 b2 = *(const float2*)(bias + o2);
    float2 mem2 = make_float2(0.f, 0.f);

    for (int i = tid; i <= T_; i += 512) cnt[i] = 0;
    unsigned int local_count = 0;
    const float* hb = h + (size_t)b * T_ * O_;
    float* ob = out + (size_t)b * T_ * O_;
    const char* dbyte = (const char*)d;
    const unsigned o2b = (unsigned)(o2 * sizeof(float));
    // zrow lives in the same d_ws allocation as d; 32-bit byte offset valid.
    const unsigned zoffb = (unsigned)((const char*)zrow - dbyte) + o2b;
    const unsigned long long below = (lane == 63) ? 0xFFFFFFFFFFFFFFFFull >> 1
                                                  : ((1ull << lane) - 1ull);

    float2 hcur = *(const float2*)(hb + o2);   // t = 0
    __syncthreads();

    for (int t = 0; t < T_; ++t) {
        const int p = t & 1, q = p ^ 1;
        const int n = cnt[t];

        float2 hnext = make_float2(0.f, 0.f);
        if (t + 1 < T_) hnext = *(const float2*)(hb + (size_t)(t + 1) * O_ + o2);

        float2 rst = make_float2(0.f, 0.f);
        for (int i = 0; i < n; i += 8) {
            unsigned offs[8];
#pragma unroll
            for (int u = 0; u < 8; ++u) {
                const int idx = i + u;
                const int j = lst[p][idx & (O_ - 1)];   // in-bounds read; value
                                                        // only used when idx<n
                offs[u] = (idx < n) ? ((unsigned)j * (unsigned)(O_ * 4) + o2b)
                                    : zoffb;
            }
            float2 v[8];
#pragma unroll
            for (int u = 0; u < 8; ++u)
                v[u] = *(const float2*)(dbyte + offs[u]);
#pragma unroll
            for (int u = 0; u < 8; ++u) { rst.x += v[u].x; rst.y += v[u].y; }
        }

        mem2.x = (mem2.x - rst.x) * betav + hcur.x * omb;
        mem2.y = (mem2.y - rst.y) * betav + hcur.y * omb;

        const int s0 = (mem2.x * invn2.x - b2.x) > 0.0f;
        const int s1 = (mem2.y * invn2.y - b2.y) > 0.0f;

        *(float2*)(ob + (size_t)t * O_ + o2) =
            make_float2(s0 ? 1.f : 0.f, s1 ? 1.f : 0.f);
        local_count += (unsigned)(s0 + s1);

        // ballot-aggregated appends into lst[q] / cnt[t+1]: ONE atomic per wave
        unsigned long long mk0 = __ballot(s0);
        unsigned long long mk1 = __ballot(s1);
        const int c0 = __popcll(mk0);
        const int tot = c0 + __popcll(mk1);
        int base = 0;
        if (lane == 0 && tot) base = atomicAdd(&cnt[t + 1], tot);
        base = __shfl(base, 0, 64);
        if (s0) lst[q][base + __popcll(mk0 & below)] = o2 + 0;
        base += c0;
        if (s1) lst[q][base + __popcll(mk1 & below)] = o2 + 1;

        barrier_lds_only();
        hcur = hnext;
    }

    red[tid] = local_count;
    __syncthreads();
    for (int st = 256; st > 0; st >>= 1) {
        if (tid < st) red[tid] += red[tid + st];
        __syncthreads();
    }
    if (tid == 0) atomicAdd(spike_count, red[0]);
}

__global__ void finalize_loss(const unsigned int* __restrict__ spike_count,
                              float* __restrict__ loss_out) {
    *loss_out = 0.5f * ((float)(*spike_count) / 16777216.0f);
}

// ---------------------------------------------------------------------------
extern "C" void kernel_launch(void* const* d_in, const int* in_sizes, int n_in,
                              void* d_out, int out_size, void* d_ws, size_t ws_size,
                              hipStream_t stream) {
    const float* x    = (const float*)d_in[0];   // [B,T,I]
    const float* w    = (const float*)d_in[1];   // [I,O]
    const float* beta = (const float*)d_in[2];   // [1]
    const float* bias = (const float*)d_in[3];   // [O]
    float* out = (float*)d_out;                  // NOUT spikes + 1 loss

    // workspace layout (~170 MB)
    char* ws = (char*)d_ws;
    float* h    = (float*)ws;                                         // 64 MiB
    float* dmat = (float*)(ws + (size_t)67108864);                    // 4 MiB
    float* invn = (float*)(ws + (size_t)71303168);                    // 4 KiB
    unsigned int* cntp = (unsigned int*)(ws + (size_t)71307264);      // 4 KiB
    unsigned short* wt_h = (unsigned short*)(ws + (size_t)71311360);  // 2 MiB
    unsigned short* wt_m = (unsigned short*)(ws + (size_t)73408512);  // 2 MiB
    unsigned short* wt_l = (unsigned short*)(ws + (size_t)75505664);  // 2 MiB
    unsigned short* x_h  = (unsigned short*)(ws + (size_t)77602816);  // 32 MiB
    unsigned short* x_m  = (unsigned short*)(ws + (size_t)111157248); // 32 MiB
    unsigned short* x_l  = (unsigned short*)(ws + (size_t)144711680); // 32 MiB
    float* zrow = (float*)x_h;   // dead after gemm_h; zeroed by gemm_wtw

    split_fused<<<16384 + 256, 256, 0, stream>>>(x, x_h, x_m, x_l,
                                                 w, wt_h, wt_m, wt_l);
    gemm_h_mfma<<<dim3(M_ / 128, O_ / 256), 512, 0, stream>>>(x_h, x_m, x_l,
                                                              wt_h, wt_m, wt_l, h);
    gemm_wtw<<<dim3(O_ / 64, O_ / 64), 256, 0, stream>>>(w, dmat, invn, cntp, zrow);
    scan_kernel<<<B_, 512, 0, stream>>>(h, dmat, invn, bias, beta, zrow, out, cntp);
    finalize_loss<<<1, 1, 0, stream>>>(cntp, out + (size_t)NOUT);
}